// Round 7
// baseline (7286.091 us; speedup 1.0000x reference)
//
#include <hip/hip_runtime.h>

#define BB   8
#define HH   128
#define WW   200
#define HWSZ 25600
#define C48  48
#define C64  64
#define NGRP 8
#define EPSV 1e-5f
#define LAMV 1e-4
#define SLOT 9830400          // BB*C48*HWSZ elements (one z/F/G slot)
#define DPB  1228800          // C48*HWSZ per-batch flat dim
#define Y64SZ 13107200        // BB*C64*HWSZ
#define BIGELEMS 131072000ull // 12*SLOT + Y64SZ

typedef unsigned short bf16_t;
typedef __attribute__((ext_vector_type(4))) short s4v;
typedef __attribute__((ext_vector_type(8))) short s8v;
typedef __attribute__((ext_vector_type(16))) float f32x16;

__device__ inline float b2f(bf16_t b) { return __uint_as_float(((unsigned)b) << 16); }
__device__ inline bf16_t f2b(float f) {
    unsigned u = __float_as_uint(f);
    unsigned r = u + 0x7fffu + ((u >> 16) & 1u);
    return (bf16_t)(r >> 16);
}
__device__ inline float ldS(const float* p) { return *p; }
__device__ inline float ldS(const bf16_t* p) { return b2f(*p); }
__device__ inline float4 ld4(const bf16_t* p) {
    ushort4 u = *(const ushort4*)p;
    return make_float4(b2f(u.x), b2f(u.y), b2f(u.z), b2f(u.w));
}
__device__ inline void st4(bf16_t* p, float4 v) {
    ushort4 u; u.x = f2b(v.x); u.y = f2b(v.y); u.z = f2b(v.z); u.w = f2b(v.w);
    *(ushort4*)p = u;
}

// (mean, invstd) from f64 sums at use site
__device__ inline void ms_from(const double* __restrict__ ds, int pair, double invcnt,
                               float& mean, float& inv) {
    double s = ds[2 * pair], q = ds[2 * pair + 1];
    double m = s * invcnt;
    double v = q * invcnt - m * m;
    mean = (float)m;
    inv = (float)(1.0 / sqrt(v + (double)EPSV));
}

// ---------------- utility ----------------

__global__ void zero_kernel(float* __restrict__ p, int n) {
    int i = blockIdx.x * 256 + threadIdx.x;
    if (i < n) p[i] = 0.f;
}
__global__ void fill16_kernel(float4* __restrict__ p) {
    float4 z; z.x = z.y = z.z = z.w = 0.f;
    p[(size_t)blockIdx.x * 256 + threadIdx.x] = z;
}
__global__ void copy16_kernel(float4* __restrict__ dst, const float4* __restrict__ src) {
    size_t i = (size_t)blockIdx.x * 256 + threadIdx.x;
    dst[i] = src[i];
}

// ---------------- weight packing: [kc][tap][mt][lane][8] bf16 ----------------
__global__ void pack_kernel(const float* __restrict__ w, bf16_t* __restrict__ apk,
                            int CIN, int CO_real, int total) {
    int idx = blockIdx.x * 256 + threadIdx.x;
    if (idx >= total) return;
    int j   = idx & 7;
    int l   = (idx >> 3) & 63;
    int mt  = (idx >> 9) & 1;
    int tap = (idx >> 10) % 9;
    int kc  = idx / 9216;
    int co = mt * 32 + (l & 31);
    int ci = kc * 16 + (l >> 5) * 8 + j;
    float v = (co < CO_real) ? w[((size_t)co * CIN + ci) * 9 + tap] : 0.f;
    apk[idx] = f2b(v);
}

// ---------------- conv0 (1->48): one (b,y) row per block, coalesced NHWC out ----------------
__global__ __launch_bounds__(256) void conv0_kernel(
    const float* __restrict__ x, const float* __restrict__ w0,
    const float* __restrict__ b0, float* __restrict__ out)
{
    __shared__ float xs[3 * 202];
    __shared__ float wt[480];
    const int tid = threadIdx.x;
    const int bI = blockIdx.x / HH, y = blockIdx.x % HH;
    for (int i = tid; i < 606; i += 256) {
        int r = i / 202, cc = i % 202;
        int gy = y + r - 1, gx = cc - 1;
        float v = 0.f;
        if ((unsigned)gy < (unsigned)HH && (unsigned)gx < (unsigned)WW)
            v = x[(size_t)bI * HWSZ + gy * WW + gx];
        xs[r * 202 + cc] = v;
    }
    for (int i = tid; i < 480; i += 256) wt[i] = (i < 432) ? w0[i] : b0[i - 432];
    __syncthreads();
    const size_t obase = (((size_t)bI * HH + y) * WW) * 48;
    for (int ch = tid; ch < 2400; ch += 256) {
        int px = (ch * 4) / 48, c0 = (ch * 4) % 48;
        float xv[3][3];
        #pragma unroll
        for (int r = 0; r < 3; r++)
            #pragma unroll
            for (int dx = 0; dx < 3; dx++)
                xv[r][dx] = xs[r * 202 + px + dx];
        float4 o;
        #pragma unroll
        for (int j = 0; j < 4; j++) {
            int c = c0 + j;
            float acc = wt[432 + c];
            #pragma unroll
            for (int r = 0; r < 3; r++)
                #pragma unroll
                for (int dx = 0; dx < 3; dx++)
                    acc = fmaf(xv[r][dx], wt[c * 9 + r * 3 + dx], acc);
            ((float*)&o)[j] = acc;
        }
        *(float4*)(out + obase + ch * 4) = o;
    }
}

// ---------------- channel-phased BN stats (fp32 src) ----------------
__global__ void bn_stats_kernel(const float* __restrict__ src, double* __restrict__ dst)
{
    __shared__ float ss[192], qq[192];
    const int tid = threadIdx.x;
    const int c = tid % 48, r = tid / 48;
    const int b = blockIdx.y;
    const size_t base = ((size_t)b * HWSZ + (size_t)blockIdx.x * 256) * 48 + c;
    float s = 0.f, q = 0.f;
    for (int p = r; p < 256; p += 4) {
        float v = src[base + (size_t)p * 48];
        s += v; q += v * v;
    }
    ss[tid] = s; qq[tid] = q;
    __syncthreads();
    if (tid < 48) {
        s = ss[tid] + ss[tid + 48] + ss[tid + 96] + ss[tid + 144];
        q = qq[tid] + qq[tid + 48] + qq[tid + 96] + qq[tid + 144];
        unsafeAtomicAdd(&dst[tid * 2],     (double)s);
        unsafeAtomicAdd(&dst[tid * 2 + 1], (double)q);
    }
}

// ---------------- BN apply: fp32 NHWC raw -> bf16 NHWC h ----------------
__global__ __launch_bounds__(256) void bn_apply_kernel(
    const float* __restrict__ src, bf16_t* __restrict__ dst,
    const float* __restrict__ gamma, const float* __restrict__ beta,
    const double* __restrict__ ds)
{
    __shared__ float gaT[48], beT[48];
    int tid = threadIdx.x;
    if (tid < 48) {
        float mean, inv; ms_from(ds, tid, 1.0 / 204800.0, mean, inv);
        float ga = gamma[tid] * inv;
        gaT[tid] = ga; beT[tid] = beta[tid] - mean * ga;
    }
    __syncthreads();
    size_t base = (size_t)blockIdx.x * 1024 + (size_t)tid * 4;
    int c0 = (int)(base % 48);
    float4 v = *(const float4*)(src + base);
    ushort4 o;
    o.x = f2b(fmaf(v.x, gaT[c0],     beT[c0]));
    o.y = f2b(fmaf(v.y, gaT[c0 + 1], beT[c0 + 1]));
    o.z = f2b(fmaf(v.z, gaT[c0 + 2], beT[c0 + 2]));
    o.w = f2b(fmaf(v.w, gaT[c0 + 3], beT[c0 + 3]));
    *(ushort4*)(dst + base) = o;
}

// ---------------- MFMA implicit-GEMM 3x3 conv + LDS-transposed epilogue + fused GN stats ----
// grid (7 x-tiles of 32, 32 y-tiles of 4, 8 b); block 256 = 4 waves (one output row each).
// Epilogue: acc -> LDS [px][co] (stride OTS) -> coalesced stores (+ADDH) -> channel-phased
// group stats with one f64 atomic pair per (block, group).
template<int CIN, int CIPAD, int CO, int OTS, int CG, bool RELU, bool ADDH, bool FOLDGN>
__global__ __launch_bounds__(256) void conv_mfma_kernel(
    const bf16_t* __restrict__ in, const s8v* __restrict__ apk,
    const bf16_t* __restrict__ hadd, bf16_t* __restrict__ out,
    double* __restrict__ dsOut,
    const double* __restrict__ dsPrev, const float* __restrict__ gPrev,
    const float* __restrict__ bPrev)
{
    constexpr int KC  = CIN / 16;
    constexpr int NCH = CIN / 4;
    const int tid  = threadIdx.x;
    const int lane = tid & 63;
    const int wv   = tid >> 6;
    const int x0 = blockIdx.x * 32;
    const int y0 = blockIdx.y * 4;
    const int b  = blockIdx.z;

    __shared__ __align__(16) bf16_t bt[6 * 34 * CIPAD];   // also reused as ot[128][OTS]
    __shared__ __align__(16) float gaT[FOLDGN ? CIN : 4];
    __shared__ __align__(16) float beT[FOLDGN ? CIN : 4];
    __shared__ float ss[256], qq[256];

    if (FOLDGN) {
        if (tid < CIN) {
            float mean, inv;
            ms_from(dsPrev, b * NGRP + tid / (CIN / NGRP), 1.0 / 204800.0, mean, inv);
            float ga = gPrev[tid] * inv;
            gaT[tid] = ga; beT[tid] = bPrev[tid] - mean * ga;
        }
        __syncthreads();
    }
    for (int i = tid; i < 6 * 34 * NCH; i += 256) {
        int ch = i % NCH, p = i / NCH;
        int r = p / 34, c = p - r * 34;
        int gy = y0 + r - 1, gx = x0 + c - 1;
        ushort4 v = make_ushort4(0, 0, 0, 0);
        if ((unsigned)gy < (unsigned)HH && (unsigned)gx < (unsigned)WW) {
            ushort4 raw = *(const ushort4*)(in + ((((size_t)b * HH + gy) * WW + gx) * CIN + ch * 4));
            if (FOLDGN) {
                float4 ga4 = *(const float4*)&gaT[ch * 4];
                float4 be4 = *(const float4*)&beT[ch * 4];
                v.x = f2b(fmaf(b2f(raw.x), ga4.x, be4.x));
                v.y = f2b(fmaf(b2f(raw.y), ga4.y, be4.y));
                v.z = f2b(fmaf(b2f(raw.z), ga4.z, be4.z));
                v.w = f2b(fmaf(b2f(raw.w), ga4.w, be4.w));
            } else v = raw;
        }
        *(ushort4*)(bt + p * CIPAD + ch * 4) = v;
    }
    __syncthreads();

    const int n = lane & 31, half = lane >> 5;
    f32x16 acc0, acc1;
    #pragma unroll
    for (int i = 0; i < 16; i++) { acc0[i] = 0.f; acc1[i] = 0.f; }

    for (int kc = 0; kc < KC; kc++) {
        s8v af[18];
        const s8v* ap = apk + (size_t)kc * 9 * 2 * 64 + lane;
        #pragma unroll
        for (int t = 0; t < 18; t++) af[t] = ap[t * 64];
        #pragma unroll
        for (int ky = 0; ky < 3; ky++)
        #pragma unroll
        for (int kx = 0; kx < 3; kx++) {
            const bf16_t* bp = bt + ((wv + ky) * 34 + n + kx) * CIPAD + kc * 16 + half * 8;
            s4v lo = *(const s4v*)bp;
            s4v hi = *(const s4v*)(bp + 4);
            s8v bfrag = __builtin_shufflevector(lo, hi, 0, 1, 2, 3, 4, 5, 6, 7);
            int t9 = (ky * 3 + kx) * 2;
            acc0 = __builtin_amdgcn_mfma_f32_32x32x16_bf16(af[t9],     bfrag, acc0, 0, 0, 0);
            acc1 = __builtin_amdgcn_mfma_f32_32x32x16_bf16(af[t9 + 1], bfrag, acc1, 0, 0, 0);
        }
    }
    __syncthreads();   // bt reads done; reuse as ot

    bf16_t* ot = bt;
    // phase 1: acc -> LDS (invalid px -> 0 so stats stay correct)
    {
        const int pxl = wv * 32 + n;
        const bool pv = (x0 + n) < WW;
        #pragma unroll
        for (int g4 = 0; g4 < 4; g4++) {
            s4v pk0;
            #pragma unroll
            for (int jj = 0; jj < 4; jj++) {
                float v = acc0[g4 * 4 + jj];
                if (RELU) v = fmaxf(v, 0.f);
                pk0[jj] = (short)(pv ? f2b(v) : (bf16_t)0);
            }
            *(s4v*)&ot[pxl * OTS + g4 * 8 + 4 * half] = pk0;
            const int c1b = 32 + g4 * 8 + 4 * half;
            if (c1b + 3 < CO) {
                s4v pk1;
                #pragma unroll
                for (int jj = 0; jj < 4; jj++) {
                    float v = acc1[g4 * 4 + jj];
                    if (RELU) v = fmaxf(v, 0.f);
                    pk1[jj] = (short)(pv ? f2b(v) : (bf16_t)0);
                }
                *(s4v*)&ot[pxl * OTS + c1b] = pk1;
            }
        }
    }
    __syncthreads();
    // phase 2: coalesced global stores (+ADDH, with LDS writeback for stats)
    {
        constexpr int NCH8 = 128 * CO / 8;
        for (int ch = tid; ch < NCH8; ch += 256) {
            int pxl = ch / (CO / 8);
            int co0 = (ch % (CO / 8)) * 8;
            int row = pxl >> 5, col = pxl & 31;
            int xx = x0 + col;
            if (xx < WW) {
                bf16_t* lp = &ot[pxl * OTS + co0];
                size_t ga = (((size_t)b * HH + y0 + row) * WW + xx) * CO + co0;
                if (ADDH) {
                    float4 h0 = ld4(hadd + ga), h1 = ld4(hadd + ga + 4);
                    float4 l0 = ld4(lp), l1 = ld4(lp + 4);
                    float4 v0 = make_float4(l0.x + h0.x, l0.y + h0.y, l0.z + h0.z, l0.w + h0.w);
                    float4 v1 = make_float4(l1.x + h1.x, l1.y + h1.y, l1.z + h1.z, l1.w + h1.w);
                    st4(out + ga, v0); st4(out + ga + 4, v1);
                    st4(lp, v0); st4(lp + 4, v1);
                } else {
                    *(ushort4*)(out + ga)     = *(ushort4*)lp;
                    *(ushort4*)(out + ga + 4) = *(ushort4*)(lp + 4);
                }
            }
        }
    }
    if (ADDH) __syncthreads();
    // phase 3: channel-phased group stats
    {
        constexpr int NPH = 256 / CO;
        const int c = tid % CO, rr = tid / CO;
        float s = 0.f, q = 0.f;
        if (rr < NPH) {
            for (int px = rr; px < 128; px += NPH) {
                float v = b2f(ot[px * OTS + c]);
                s += v; q += v * v;
            }
        }
        ss[tid] = s; qq[tid] = q;
        __syncthreads();
        if (tid < CO) {
            float S = ss[tid], Q = qq[tid];
            #pragma unroll
            for (int p = 1; p < NPH; p++) { S += ss[tid + p * CO]; Q += qq[tid + p * CO]; }
            ss[tid] = S; qq[tid] = Q;
        }
        __syncthreads();
        if (tid < NGRP) {
            float S = 0.f, Q = 0.f;
            #pragma unroll
            for (int j = 0; j < CG; j++) { S += ss[tid * CG + j]; Q += qq[tid * CG + j]; }
            unsafeAtomicAdd(&dsOut[((size_t)b * NGRP + tid) * 2],     (double)S);
            unsafeAtomicAdd(&dsOut[((size_t)b * NGRP + tid) * 2 + 1], (double)Q);
        }
    }
}

// ---------------- v = relu(z + gn2(u)) in place on u, channel-phased gn3 stats ----------------
__global__ __launch_bounds__(192) void add_relu_gn2_kernel(
    bf16_t* __restrict__ u, const bf16_t* __restrict__ z,
    const double* __restrict__ ds2, const float* __restrict__ g2,
    const float* __restrict__ b2, double* __restrict__ ds3, int pxPerBlock)
{
    __shared__ float ss[192], qq[192];
    const int tid = threadIdx.x;
    const int c = tid % 48, r = tid / 48;
    const int b = blockIdx.y;
    float mean, inv; ms_from(ds2, b * NGRP + c / 6, 1.0 / 153600.0, mean, inv);
    const float ga = g2[c] * inv;
    const float be = b2[c] - mean * ga;
    const size_t base = ((size_t)b * HWSZ + (size_t)blockIdx.x * pxPerBlock) * 48 + c;
    float s = 0.f, q = 0.f;
    for (int p = r; p < pxPerBlock; p += 4) {
        size_t idx = base + (size_t)p * 48;
        float v = fmaxf(fmaf(b2f(u[idx]), ga, be) + b2f(z[idx]), 0.f);
        u[idx] = f2b(v);
        s += v; q += v * v;
    }
    ss[tid] = s; qq[tid] = q;
    __syncthreads();
    if (tid < 48) {
        s = ss[tid] + ss[tid + 48] + ss[tid + 96] + ss[tid + 144];
        q = qq[tid] + qq[tid + 48] + qq[tid + 96] + qq[tid + 144];
        ss[tid] = s; qq[tid] = q;
    }
    __syncthreads();
    if (tid < NGRP) {
        float S = 0.f, Q = 0.f;
        #pragma unroll
        for (int j = 0; j < 6; j++) { S += ss[tid * 6 + j]; Q += qq[tid * 6 + j]; }
        unsafeAtomicAdd(&ds3[(b * NGRP + tid) * 2],     (double)S);
        unsafeAtomicAdd(&ds3[(b * NGRP + tid) * 2 + 1], (double)Q);
    }
}

// ---------------- gn3 apply + fused Gram row update ----------------
// F = gn3(v); if nf>0: G_j = F - z (written), gram[j][i] += G_j . G_i for i<nf
__global__ __launch_bounds__(256) void gn3_gram_kernel(
    const bf16_t* __restrict__ v, const bf16_t* __restrict__ z,
    bf16_t* __restrict__ F, bf16_t* __restrict__ G,
    const double* __restrict__ ds3, const float* __restrict__ g3,
    const float* __restrict__ b3,
    const bf16_t* __restrict__ Gall, int jslot, int nf, double* __restrict__ gram)
{
    __shared__ float gaT[48], beT[48];
    __shared__ double red[4 * 5];
    int tid = threadIdx.x;
    int b = blockIdx.x / 600;
    if (tid < 48) {
        float mean, inv; ms_from(ds3, b * NGRP + tid / 6, 1.0 / 153600.0, mean, inv);
        float ga = g3[tid] * inv;
        gaT[tid] = ga; beT[tid] = b3[tid] - mean * ga;
    }
    __syncthreads();
    size_t base = (size_t)blockIdx.x * 2048 + (size_t)tid * 8;
    int c0 = (int)(base % 48);
    float4 vA = ld4(v + base), vB = ld4(v + base + 4);
    float rr[8] = {vA.x, vA.y, vA.z, vA.w, vB.x, vB.y, vB.z, vB.w};
    #pragma unroll
    for (int e = 0; e < 8; e++) rr[e] = fmaf(rr[e], gaT[c0 + e], beT[c0 + e]);
    st4(F + base,     make_float4(rr[0], rr[1], rr[2], rr[3]));
    st4(F + base + 4, make_float4(rr[4], rr[5], rr[6], rr[7]));
    if (nf > 0) {
        float4 zA = ld4(z + base), zB = ld4(z + base + 4);
        float gg[8] = {rr[0] - zA.x, rr[1] - zA.y, rr[2] - zA.z, rr[3] - zA.w,
                       rr[4] - zB.x, rr[5] - zB.y, rr[6] - zB.z, rr[7] - zB.w};
        st4(G + base,     make_float4(gg[0], gg[1], gg[2], gg[3]));
        st4(G + base + 4, make_float4(gg[4], gg[5], gg[6], gg[7]));
        double dot[5] = {0.0, 0.0, 0.0, 0.0, 0.0};
        #pragma unroll
        for (int i = 0; i < 5; i++) {
            if (i >= nf) continue;
            if (i == jslot) {
                float d = 0.f;
                #pragma unroll
                for (int e = 0; e < 8; e++) d += gg[e] * gg[e];
                dot[i] = (double)d;
            } else {
                const bf16_t* gp = Gall + (size_t)i * SLOT + base;
                float4 gA = ld4(gp), gB = ld4(gp + 4);
                float d = gg[0] * gA.x + gg[1] * gA.y + gg[2] * gA.z + gg[3] * gA.w
                        + gg[4] * gB.x + gg[5] * gB.y + gg[6] * gB.z + gg[7] * gB.w;
                dot[i] = (double)d;
            }
        }
        #pragma unroll
        for (int i = 0; i < 5; i++) {
            if (i >= nf) continue;
            #pragma unroll
            for (int off = 32; off > 0; off >>= 1) dot[i] += __shfl_down(dot[i], off);
        }
        int wv = tid >> 6;
        if ((tid & 63) == 0) {
            #pragma unroll
            for (int i = 0; i < 5; i++) if (i < nf) red[wv * 5 + i] = dot[i];
        }
        __syncthreads();
        if (tid == 0) {
            #pragma unroll
            for (int i = 0; i < 5; i++) {
                if (i >= nf) continue;
                double D = red[i] + red[5 + i] + red[10 + i] + red[15 + i];
                unsafeAtomicAdd(&gram[b * 25 + jslot * 5 + i], D);
                if (i != jslot) unsafeAtomicAdd(&gram[b * 25 + i * 5 + jslot], D);
            }
        }
    }
}

// ---------------- Anderson solve + xk ----------------

__global__ void solve_kernel(const double* __restrict__ gram, float* __restrict__ alpha, int n) {
    int b = threadIdx.x;
    if (b >= BB) return;
    const int m = n + 1;
    double A[6][7];
    for (int i = 0; i < m; i++)
        for (int jj = 0; jj <= m; jj++) A[i][jj] = 0.0;
    for (int i = 1; i < m; i++) { A[0][i] = 1.0; A[i][0] = 1.0; }
    for (int i = 1; i < m; i++)
        for (int jj = 1; jj < m; jj++)
            A[i][jj] = gram[b * 25 + (i - 1) * 5 + (jj - 1)] + ((i == jj) ? LAMV : 0.0);
    A[0][m] = 1.0;
    for (int col = 0; col < m; col++) {
        int piv = col; double best = fabs(A[col][col]);
        for (int rr = col + 1; rr < m; rr++) {
            double tv = fabs(A[rr][col]);
            if (tv > best) { best = tv; piv = rr; }
        }
        if (piv != col)
            for (int cc = col; cc <= m; cc++) {
                double tmp = A[col][cc]; A[col][cc] = A[piv][cc]; A[piv][cc] = tmp;
            }
        double invp = 1.0 / A[col][col];
        for (int cc = col; cc <= m; cc++) A[col][cc] *= invp;
        for (int rr = 0; rr < m; rr++) {
            if (rr == col) continue;
            double f = A[rr][col];
            if (f != 0.0)
                for (int cc = col; cc <= m; cc++) A[rr][cc] = fma(-f, A[col][cc], A[rr][cc]);
        }
    }
    for (int i = 0; i < n; i++) alpha[b * 5 + i] = (float)A[i + 1][m];
}

__global__ __launch_bounds__(256) void xk_kernel(
    const bf16_t* __restrict__ Fb, const float* __restrict__ alpha,
    bf16_t* __restrict__ zcur, int n, double* __restrict__ gram, int jz, int nf)
{
    if (blockIdx.x == 0 && threadIdx.x < 8 * nf) {
        int b = threadIdx.x / nf, i = threadIdx.x % nf;
        gram[b * 25 + jz * 5 + i] = 0.0;
        gram[b * 25 + i * 5 + jz] = 0.0;
    }
    size_t idx = ((size_t)blockIdx.x * 256 + threadIdx.x) * 4;
    int b = (int)(idx / DPB);
    float4 s; s.x = s.y = s.z = s.w = 0.f;
    #pragma unroll
    for (int j = 0; j < 5; j++) {
        if (j < n) {
            float al = alpha[b * 5 + j];
            float4 f = ld4(Fb + (size_t)j * SLOT + idx);
            s.x = fmaf(f.x, al, s.x); s.y = fmaf(f.y, al, s.y);
            s.z = fmaf(f.z, al, s.z); s.w = fmaf(f.w, al, s.w);
        }
    }
    st4(zcur + idx, s);
}

// ---------------- final linear (NHWC bf16 in) ----------------
__global__ __launch_bounds__(512) void fc_kernel(
    const bf16_t* __restrict__ zf, const float* __restrict__ fw,
    const float* __restrict__ fb, float* __restrict__ out)
{
    __shared__ bf16_t row[9600];
    __shared__ float fwT[2000];
    int tid = threadIdx.x;
    int b = blockIdx.x >> 7, hh = blockIdx.x & 127;
    size_t base = (((size_t)b * HH + hh) * WW) * 48;
    for (int i = tid; i < 2400; i += 512)
        *(ushort4*)&row[i * 4] = *(const ushort4*)(zf + base + (size_t)i * 4);
    for (int i = tid; i < 2000; i += 512) fwT[i] = fw[i];
    __syncthreads();
    if (tid < 480) {
        int c = tid % 48, o = tid / 48;
        float acc = fb[o];
        #pragma unroll 4
        for (int w = 0; w < 200; w++)
            acc = fmaf(b2f(row[w * 48 + c]), fwT[o * 200 + w], acc);
        out[(((size_t)b * 48 + c) * HH + hh) * 10 + o] = acc;
    }
}

// ---------------- host ----------------

static inline int imin(int a, int b) { return a < b ? a : b; }

extern "C" void kernel_launch(void* const* d_in, const int* in_sizes, int n_in,
                              void* d_out, int out_size, void* d_ws, size_t ws_size,
                              hipStream_t stream)
{
    const float* x   = (const float*)d_in[0];
    const float* w0  = (const float*)d_in[1];
    const float* b0  = (const float*)d_in[2];
    const float* bng = (const float*)d_in[3];
    const float* bnb = (const float*)d_in[4];
    const float* w1  = (const float*)d_in[5];
    const float* w2  = (const float*)d_in[6];
    const float* g1  = (const float*)d_in[7];
    const float* be1 = (const float*)d_in[8];
    const float* g2  = (const float*)d_in[9];
    const float* be2 = (const float*)d_in[10];
    const float* g3  = (const float*)d_in[11];
    const float* be3 = (const float*)d_in[12];
    const float* fcw = (const float*)d_in[13];
    const float* fcb = (const float*)d_in[14];
    float* out = (float*)d_out;

    bf16_t* h    = (bf16_t*)d_ws;           // SLOT    (NHWC)
    bf16_t* zcur = h + (size_t)SLOT;        // SLOT
    bf16_t* y64  = zcur + (size_t)SLOT;     // Y64SZ
    bf16_t* Fb   = y64 + (size_t)Y64SZ;     // 5*SLOT
    bf16_t* Gb   = Fb + 5 * (size_t)SLOT;   // 5*SLOT
    double* dstats = (double*)((char*)d_ws + BIGELEMS * 2);  // 9696 dbl: BN 96 + 25*384
    double* gram   = dstats + 9696;                          // 200 dbl
    float*  alpha  = (float*)(gram + 200);                   // 40 f
    bf16_t* apk1   = (bf16_t*)(alpha + 40);                  // 27648
    bf16_t* apk2   = apk1 + 27648;                           // 36864
    float*  scratch = (float*)Gb;  // conv0 raw fp32 (G region dead at that point)

    const size_t need = BIGELEMS * 2 + 9696 * 8 + 200 * 8 + 40 * 4 + (27648 + 36864) * 2;
    if (ws_size < need) return;

    const dim3 blk(256);
    const int SLOT_QBLK = SLOT / 4 / 256;       // 9600
    const int CHUNKS16  = SLOT * 2 / 16 / 256;  // 4800

    zero_kernel<<<(19792 + 255) / 256, blk, 0, stream>>>((float*)dstats, 19792);
    pack_kernel<<<108, blk, 0, stream>>>(w1, apk1, 48, 64, 27648);
    pack_kernel<<<144, blk, 0, stream>>>(w2, apk2, 64, 48, 36864);
    fill16_kernel<<<CHUNKS16, blk, 0, stream>>>((float4*)zcur);

    // h = BN(conv0(x)+b0) in NHWC bf16
    conv0_kernel<<<BB * HH, blk, 0, stream>>>(x, w0, b0, scratch);
    bn_stats_kernel<<<dim3(100, BB), dim3(192), 0, stream>>>(scratch, dstats);
    bn_apply_kernel<<<SLOT / 1024, blk, 0, stream>>>(scratch, h, bng, bnb, dstats);

    int call = 0;
    auto resnet = [&](const bf16_t* zin, bf16_t* Fdst, bf16_t* Gdst, int jslot, int nf) {
        double* ds = dstats + 96 + 384 * call;  // ds1 = +0, ds2 = +128, ds3 = +256 (64 pairs each)
        call++;
        dim3 cg(7, 32, BB);
        conv_mfma_kernel<48, 52, 64, 66, 8, true, false, false><<<cg, blk, 0, stream>>>(
            zin, (const s8v*)apk1, nullptr, y64, ds, nullptr, nullptr, nullptr);
        conv_mfma_kernel<64, 68, 48, 50, 6, false, true, true><<<cg, blk, 0, stream>>>(
            y64, (const s8v*)apk2, h, Fdst, ds + 128, ds, g1, be1);
        add_relu_gn2_kernel<<<dim3(100, BB), dim3(192), 0, stream>>>(
            Fdst, zin, ds + 128, g2, be2, ds + 256, 256);
        gn3_gram_kernel<<<SLOT / 2048, blk, 0, stream>>>(
            Fdst, zin, Fdst, Gdst, ds + 256, g3, be3, Gb, jslot, nf, gram);
    };

    // slot 0: X=0, F0=f(0), G0=F0 (gram[0,0] accumulated in gn3)
    resnet(zcur, Fb, Gb, 0, 1);
    // slot 1: X=F0, F1=f(F0), G1=F1-F0 (gram row/col 1, n=2)
    copy16_kernel<<<CHUNKS16, blk, 0, stream>>>((float4*)zcur, (const float4*)Fb);
    resnet(zcur, Fb + (size_t)SLOT, Gb + (size_t)SLOT, 1, 2);

    for (int k = 2; k <= 24; k++) {
        int n = imin(k, 5);
        int j = k % 5;
        int nf = imin(k + 1, 5);
        solve_kernel<<<1, 64, 0, stream>>>(gram, alpha, n);
        // xk also zeroes gram row/col j (after solve consumed the old gram)
        xk_kernel<<<SLOT_QBLK, blk, 0, stream>>>(Fb, alpha, zcur, n, gram, j, nf);
        if (k < 24)   // reference computes Fv at k=24 but never uses it
            resnet(zcur, Fb + (size_t)j * SLOT, Gb + (size_t)j * SLOT, j, nf);
    }

    // z_star = zcur; one extra f application into F slot 0 (no G, no gram)
    resnet(zcur, Fb, nullptr, 0, 0);

    // final linear: NHWC [8,128,200,48] x fw[10,200] -> out [8,48,128,10]
    fc_kernel<<<BB * HH, dim3(512), 0, stream>>>(Fb, fcw, fcb, out);
}

// Round 8
// 5289.504 us; speedup vs baseline: 1.3775x; 1.3775x over previous
//
#include <hip/hip_runtime.h>

#define BB   8
#define HH   128
#define WW   200
#define HWSZ 25600
#define C48  48
#define C64  64
#define NGRP 8
#define EPSV 1e-5f
#define LAMV 1e-4
#define SLOT 9830400          // BB*C48*HWSZ elements (one z/F/G slot)
#define DPB  1228800          // C48*HWSZ per-batch flat dim
#define Y64SZ 13107200        // BB*C64*HWSZ
#define BIGELEMS 131072000ull // 12*SLOT + Y64SZ

typedef unsigned short bf16_t;
typedef __attribute__((ext_vector_type(4))) short s4v;
typedef __attribute__((ext_vector_type(8))) short s8v;
typedef __attribute__((ext_vector_type(16))) float f32x16;

__device__ inline float b2f(bf16_t b) { return __uint_as_float(((unsigned)b) << 16); }
__device__ inline bf16_t f2b(float f) {
    unsigned u = __float_as_uint(f);
    unsigned r = u + 0x7fffu + ((u >> 16) & 1u);
    return (bf16_t)(r >> 16);
}
__device__ inline float lo16(unsigned u) { return __uint_as_float(u << 16); }
__device__ inline float hi16(unsigned u) { return __uint_as_float(u & 0xffff0000u); }
__device__ inline unsigned pack2(float lo, float hi) {
    return ((unsigned)f2b(lo)) | (((unsigned)f2b(hi)) << 16);
}
__device__ inline float4 ld4(const bf16_t* p) {
    ushort4 u = *(const ushort4*)p;
    return make_float4(b2f(u.x), b2f(u.y), b2f(u.z), b2f(u.w));
}
__device__ inline void st4(bf16_t* p, float4 v) {
    ushort4 u; u.x = f2b(v.x); u.y = f2b(v.y); u.z = f2b(v.z); u.w = f2b(v.w);
    *(ushort4*)p = u;
}
// 8 bf16 <-> 8 floats via one 16B op
__device__ inline void ld8(const bf16_t* p, float* v) {
    uint4 u = *(const uint4*)p;
    v[0] = lo16(u.x); v[1] = hi16(u.x); v[2] = lo16(u.y); v[3] = hi16(u.y);
    v[4] = lo16(u.z); v[5] = hi16(u.z); v[6] = lo16(u.w); v[7] = hi16(u.w);
}
__device__ inline void st8(bf16_t* p, const float* v) {
    uint4 u;
    u.x = pack2(v[0], v[1]); u.y = pack2(v[2], v[3]);
    u.z = pack2(v[4], v[5]); u.w = pack2(v[6], v[7]);
    *(uint4*)p = u;
}

// (mean, invstd) from f64 sums at use site
__device__ inline void ms_from(const double* __restrict__ ds, int pair, double invcnt,
                               float& mean, float& inv) {
    double s = ds[2 * pair], q = ds[2 * pair + 1];
    double m = s * invcnt;
    double v = q * invcnt - m * m;
    mean = (float)m;
    inv = (float)(1.0 / sqrt(v + (double)EPSV));
}

// ---------------- utility ----------------

__global__ void zero_kernel(float* __restrict__ p, int n) {
    int i = blockIdx.x * 256 + threadIdx.x;
    if (i < n) p[i] = 0.f;
}
__global__ void fill16_kernel(float4* __restrict__ p) {
    float4 z; z.x = z.y = z.z = z.w = 0.f;
    p[(size_t)blockIdx.x * 256 + threadIdx.x] = z;
}
__global__ void copy16_kernel(float4* __restrict__ dst, const float4* __restrict__ src) {
    size_t i = (size_t)blockIdx.x * 256 + threadIdx.x;
    dst[i] = src[i];
}

// ---------------- weight packing: [kc][tap][mt][lane][8] bf16 ----------------
__global__ void pack_kernel(const float* __restrict__ w, bf16_t* __restrict__ apk,
                            int CIN, int CO_real, int total) {
    int idx = blockIdx.x * 256 + threadIdx.x;
    if (idx >= total) return;
    int j   = idx & 7;
    int l   = (idx >> 3) & 63;
    int mt  = (idx >> 9) & 1;
    int tap = (idx >> 10) % 9;
    int kc  = idx / 9216;
    int co = mt * 32 + (l & 31);
    int ci = kc * 16 + (l >> 5) * 8 + j;
    float v = (co < CO_real) ? w[((size_t)co * CIN + ci) * 9 + tap] : 0.f;
    apk[idx] = f2b(v);
}

// ---------------- conv0 (1->48): one (b,y) row per block, coalesced NHWC out ----------------
__global__ __launch_bounds__(256) void conv0_kernel(
    const float* __restrict__ x, const float* __restrict__ w0,
    const float* __restrict__ b0, float* __restrict__ out)
{
    __shared__ float xs[3 * 202];
    __shared__ float wt[480];
    const int tid = threadIdx.x;
    const int bI = blockIdx.x / HH, y = blockIdx.x % HH;
    for (int i = tid; i < 606; i += 256) {
        int r = i / 202, cc = i % 202;
        int gy = y + r - 1, gx = cc - 1;
        float v = 0.f;
        if ((unsigned)gy < (unsigned)HH && (unsigned)gx < (unsigned)WW)
            v = x[(size_t)bI * HWSZ + gy * WW + gx];
        xs[r * 202 + cc] = v;
    }
    for (int i = tid; i < 480; i += 256) wt[i] = (i < 432) ? w0[i] : b0[i - 432];
    __syncthreads();
    const size_t obase = (((size_t)bI * HH + y) * WW) * 48;
    for (int ch = tid; ch < 2400; ch += 256) {
        int px = (ch * 4) / 48, c0 = (ch * 4) % 48;
        float xv[3][3];
        #pragma unroll
        for (int r = 0; r < 3; r++)
            #pragma unroll
            for (int dx = 0; dx < 3; dx++)
                xv[r][dx] = xs[r * 202 + px + dx];
        float4 o;
        #pragma unroll
        for (int j = 0; j < 4; j++) {
            int c = c0 + j;
            float acc = wt[432 + c];
            #pragma unroll
            for (int r = 0; r < 3; r++)
                #pragma unroll
                for (int dx = 0; dx < 3; dx++)
                    acc = fmaf(xv[r][dx], wt[c * 9 + r * 3 + dx], acc);
            ((float*)&o)[j] = acc;
        }
        *(float4*)(out + obase + ch * 4) = o;
    }
}

// ---------------- channel-phased BN stats (fp32 src) ----------------
__global__ void bn_stats_kernel(const float* __restrict__ src, double* __restrict__ dst)
{
    __shared__ float ss[192], qq[192];
    const int tid = threadIdx.x;
    const int c = tid % 48, r = tid / 48;
    const int b = blockIdx.y;
    const size_t base = ((size_t)b * HWSZ + (size_t)blockIdx.x * 256) * 48 + c;
    float s = 0.f, q = 0.f;
    for (int p = r; p < 256; p += 4) {
        float v = src[base + (size_t)p * 48];
        s += v; q += v * v;
    }
    ss[tid] = s; qq[tid] = q;
    __syncthreads();
    if (tid < 48) {
        s = ss[tid] + ss[tid + 48] + ss[tid + 96] + ss[tid + 144];
        q = qq[tid] + qq[tid + 48] + qq[tid + 96] + qq[tid + 144];
        unsafeAtomicAdd(&dst[tid * 2],     (double)s);
        unsafeAtomicAdd(&dst[tid * 2 + 1], (double)q);
    }
}

// ---------------- BN apply: fp32 NHWC raw -> bf16 NHWC h ----------------
__global__ __launch_bounds__(256) void bn_apply_kernel(
    const float* __restrict__ src, bf16_t* __restrict__ dst,
    const float* __restrict__ gamma, const float* __restrict__ beta,
    const double* __restrict__ ds)
{
    __shared__ float gaT[48], beT[48];
    int tid = threadIdx.x;
    if (tid < 48) {
        float mean, inv; ms_from(ds, tid, 1.0 / 204800.0, mean, inv);
        float ga = gamma[tid] * inv;
        gaT[tid] = ga; beT[tid] = beta[tid] - mean * ga;
    }
    __syncthreads();
    size_t base = (size_t)blockIdx.x * 1024 + (size_t)tid * 4;
    int c0 = (int)(base % 48);
    float4 v = *(const float4*)(src + base);
    ushort4 o;
    o.x = f2b(fmaf(v.x, gaT[c0],     beT[c0]));
    o.y = f2b(fmaf(v.y, gaT[c0 + 1], beT[c0 + 1]));
    o.z = f2b(fmaf(v.z, gaT[c0 + 2], beT[c0 + 2]));
    o.w = f2b(fmaf(v.w, gaT[c0 + 3], beT[c0 + 3]));
    *(ushort4*)(dst + base) = o;
}

// ---------------- MFMA implicit-GEMM 3x3 conv + LDS-transposed epilogue + fused GN stats ----
template<int CIN, int CIPAD, int CO, int OTS, int CG, bool RELU, bool ADDH, bool FOLDGN>
__global__ __launch_bounds__(256) void conv_mfma_kernel(
    const bf16_t* __restrict__ in, const s8v* __restrict__ apk,
    const bf16_t* __restrict__ hadd, bf16_t* __restrict__ out,
    double* __restrict__ dsOut,
    const double* __restrict__ dsPrev, const float* __restrict__ gPrev,
    const float* __restrict__ bPrev)
{
    constexpr int KC  = CIN / 16;
    constexpr int NCH = CIN / 4;
    const int tid  = threadIdx.x;
    const int lane = tid & 63;
    const int wv   = tid >> 6;
    const int x0 = blockIdx.x * 32;
    const int y0 = blockIdx.y * 4;
    const int b  = blockIdx.z;

    __shared__ __align__(16) bf16_t bt[6 * 34 * CIPAD];   // also reused as ot[128][OTS]
    __shared__ __align__(16) float gaT[FOLDGN ? CIN : 4];
    __shared__ __align__(16) float beT[FOLDGN ? CIN : 4];
    __shared__ float ss[256], qq[256];

    if (FOLDGN) {
        if (tid < CIN) {
            float mean, inv;
            ms_from(dsPrev, b * NGRP + tid / (CIN / NGRP), 1.0 / 204800.0, mean, inv);
            float ga = gPrev[tid] * inv;
            gaT[tid] = ga; beT[tid] = bPrev[tid] - mean * ga;
        }
        __syncthreads();
    }
    for (int i = tid; i < 6 * 34 * NCH; i += 256) {
        int ch = i % NCH, p = i / NCH;
        int r = p / 34, c = p - r * 34;
        int gy = y0 + r - 1, gx = x0 + c - 1;
        ushort4 v = make_ushort4(0, 0, 0, 0);
        if ((unsigned)gy < (unsigned)HH && (unsigned)gx < (unsigned)WW) {
            ushort4 raw = *(const ushort4*)(in + ((((size_t)b * HH + gy) * WW + gx) * CIN + ch * 4));
            if (FOLDGN) {
                float4 ga4 = *(const float4*)&gaT[ch * 4];
                float4 be4 = *(const float4*)&beT[ch * 4];
                v.x = f2b(fmaf(b2f(raw.x), ga4.x, be4.x));
                v.y = f2b(fmaf(b2f(raw.y), ga4.y, be4.y));
                v.z = f2b(fmaf(b2f(raw.z), ga4.z, be4.z));
                v.w = f2b(fmaf(b2f(raw.w), ga4.w, be4.w));
            } else v = raw;
        }
        *(ushort4*)(bt + p * CIPAD + ch * 4) = v;
    }
    __syncthreads();

    const int n = lane & 31, half = lane >> 5;
    f32x16 acc0, acc1;
    #pragma unroll
    for (int i = 0; i < 16; i++) { acc0[i] = 0.f; acc1[i] = 0.f; }

    for (int kc = 0; kc < KC; kc++) {
        s8v af[18];
        const s8v* ap = apk + (size_t)kc * 9 * 2 * 64 + lane;
        #pragma unroll
        for (int t = 0; t < 18; t++) af[t] = ap[t * 64];
        #pragma unroll
        for (int ky = 0; ky < 3; ky++)
        #pragma unroll
        for (int kx = 0; kx < 3; kx++) {
            const bf16_t* bp = bt + ((wv + ky) * 34 + n + kx) * CIPAD + kc * 16 + half * 8;
            s4v lo = *(const s4v*)bp;
            s4v hi = *(const s4v*)(bp + 4);
            s8v bfrag = __builtin_shufflevector(lo, hi, 0, 1, 2, 3, 4, 5, 6, 7);
            int t9 = (ky * 3 + kx) * 2;
            acc0 = __builtin_amdgcn_mfma_f32_32x32x16_bf16(af[t9],     bfrag, acc0, 0, 0, 0);
            acc1 = __builtin_amdgcn_mfma_f32_32x32x16_bf16(af[t9 + 1], bfrag, acc1, 0, 0, 0);
        }
    }
    __syncthreads();   // bt reads done; reuse as ot

    bf16_t* ot = bt;
    {
        const int pxl = wv * 32 + n;
        const bool pv = (x0 + n) < WW;
        #pragma unroll
        for (int g4 = 0; g4 < 4; g4++) {
            s4v pk0;
            #pragma unroll
            for (int jj = 0; jj < 4; jj++) {
                float v = acc0[g4 * 4 + jj];
                if (RELU) v = fmaxf(v, 0.f);
                pk0[jj] = (short)(pv ? f2b(v) : (bf16_t)0);
            }
            *(s4v*)&ot[pxl * OTS + g4 * 8 + 4 * half] = pk0;
            const int c1b = 32 + g4 * 8 + 4 * half;
            if (c1b + 3 < CO) {
                s4v pk1;
                #pragma unroll
                for (int jj = 0; jj < 4; jj++) {
                    float v = acc1[g4 * 4 + jj];
                    if (RELU) v = fmaxf(v, 0.f);
                    pk1[jj] = (short)(pv ? f2b(v) : (bf16_t)0);
                }
                *(s4v*)&ot[pxl * OTS + c1b] = pk1;
            }
        }
    }
    __syncthreads();
    {
        constexpr int NCH8 = 128 * CO / 8;
        for (int ch = tid; ch < NCH8; ch += 256) {
            int pxl = ch / (CO / 8);
            int co0 = (ch % (CO / 8)) * 8;
            int row = pxl >> 5, col = pxl & 31;
            int xx = x0 + col;
            if (xx < WW) {
                bf16_t* lp = &ot[pxl * OTS + co0];
                size_t ga = (((size_t)b * HH + y0 + row) * WW + xx) * CO + co0;
                if (ADDH) {
                    float4 h0 = ld4(hadd + ga), h1 = ld4(hadd + ga + 4);
                    float4 l0 = ld4(lp), l1 = ld4(lp + 4);
                    float4 v0 = make_float4(l0.x + h0.x, l0.y + h0.y, l0.z + h0.z, l0.w + h0.w);
                    float4 v1 = make_float4(l1.x + h1.x, l1.y + h1.y, l1.z + h1.z, l1.w + h1.w);
                    st4(out + ga, v0); st4(out + ga + 4, v1);
                    st4(lp, v0); st4(lp + 4, v1);
                } else {
                    *(ushort4*)(out + ga)     = *(ushort4*)lp;
                    *(ushort4*)(out + ga + 4) = *(ushort4*)(lp + 4);
                }
            }
        }
    }
    if (ADDH) __syncthreads();
    {
        constexpr int NPH = 256 / CO;
        const int c = tid % CO, rr = tid / CO;
        float s = 0.f, q = 0.f;
        if (rr < NPH) {
            for (int px = rr; px < 128; px += NPH) {
                float v = b2f(ot[px * OTS + c]);
                s += v; q += v * v;
            }
        }
        ss[tid] = s; qq[tid] = q;
        __syncthreads();
        if (tid < CO) {
            float S = ss[tid], Q = qq[tid];
            #pragma unroll
            for (int p = 1; p < NPH; p++) { S += ss[tid + p * CO]; Q += qq[tid + p * CO]; }
            ss[tid] = S; qq[tid] = Q;
        }
        __syncthreads();
        if (tid < NGRP) {
            float S = 0.f, Q = 0.f;
            #pragma unroll
            for (int j = 0; j < CG; j++) { S += ss[tid * CG + j]; Q += qq[tid * CG + j]; }
            unsafeAtomicAdd(&dsOut[((size_t)b * NGRP + tid) * 2],     (double)S);
            unsafeAtomicAdd(&dsOut[((size_t)b * NGRP + tid) * 2 + 1], (double)Q);
        }
    }
}

// ---------------- v = relu(z + gn2(u)) in place on u, looped + register group stats ----------
// 192 threads: c0 = 8*(tid%6) fixed -> per-thread group pair constant; px-strided x8 iters.
__global__ __launch_bounds__(192) void add_relu_gn2_kernel(
    bf16_t* __restrict__ u, const bf16_t* __restrict__ z,
    const double* __restrict__ ds2, const float* __restrict__ g2,
    const float* __restrict__ b2, double* __restrict__ ds3)
{
    __shared__ float sm[16];
    const int tid = threadIdx.x;
    const int c0 = 8 * (tid % 6), pxr = tid / 6;
    const int b = blockIdx.y;
    if (tid < 16) sm[tid] = 0.f;
    const int gA = c0 / 6;
    const int split = (gA + 1) * 6 - c0;
    float meanA, invA, meanB, invB;
    ms_from(ds2, b * NGRP + gA,     1.0 / 153600.0, meanA, invA);
    ms_from(ds2, b * NGRP + gA + 1, 1.0 / 153600.0, meanB, invB);
    float wga[8], wbe[8];
    #pragma unroll
    for (int e = 0; e < 8; e++) {
        int c = c0 + e;
        float m = (e < split) ? meanA : meanB, iv = (e < split) ? invA : invB;
        float ga = g2[c] * iv;
        wga[e] = ga; wbe[e] = b2[c] - m * ga;
    }
    __syncthreads();
    const size_t pxbase = (size_t)b * HWSZ + (size_t)blockIdx.x * 256;
    float sA = 0.f, qA = 0.f, sB = 0.f, qB = 0.f;
    for (int it = 0; it < 8; it++) {
        size_t idx = (pxbase + it * 32 + pxr) * 48 + c0;
        float uu[8], zz[8], vv[8];
        ld8(u + idx, uu); ld8(z + idx, zz);
        #pragma unroll
        for (int e = 0; e < 8; e++) {
            float v = fmaxf(fmaf(uu[e], wga[e], wbe[e]) + zz[e], 0.f);
            vv[e] = v;
            if (e < split) { sA += v; qA += v * v; } else { sB += v; qB += v * v; }
        }
        st8(u + idx, vv);
    }
    atomicAdd(&sm[2 * gA], sA);     atomicAdd(&sm[2 * gA + 1], qA);
    atomicAdd(&sm[2 * gA + 2], sB); atomicAdd(&sm[2 * gA + 3], qB);
    __syncthreads();
    if (tid < NGRP) {
        unsafeAtomicAdd(&ds3[(b * NGRP + tid) * 2],     (double)sm[tid * 2]);
        unsafeAtomicAdd(&ds3[(b * NGRP + tid) * 2 + 1], (double)sm[tid * 2 + 1]);
    }
}

// ---------------- gn3 apply + fused Gram row, looped (MLP) ----------------
// 192 threads, c0 fixed per thread, px-strided x8; f64 dot accumulation across iters.
__global__ __launch_bounds__(192) void gn3_gram_kernel(
    const bf16_t* __restrict__ v, const bf16_t* __restrict__ z,
    bf16_t* __restrict__ F, bf16_t* __restrict__ G,
    const double* __restrict__ ds3, const float* __restrict__ g3,
    const float* __restrict__ b3,
    const bf16_t* __restrict__ Gall, int jslot, int nf, double* __restrict__ gram)
{
    __shared__ double red[3][5];
    const int tid = threadIdx.x;
    const int c0 = 8 * (tid % 6), pxr = tid / 6;
    const int b = blockIdx.y;
    const int gA = c0 / 6;
    const int split = (gA + 1) * 6 - c0;
    float meanA, invA, meanB, invB;
    ms_from(ds3, b * NGRP + gA,     1.0 / 153600.0, meanA, invA);
    ms_from(ds3, b * NGRP + gA + 1, 1.0 / 153600.0, meanB, invB);
    float wga[8], wbe[8];
    #pragma unroll
    for (int e = 0; e < 8; e++) {
        int c = c0 + e;
        float m = (e < split) ? meanA : meanB, iv = (e < split) ? invA : invB;
        float ga = g3[c] * iv;
        wga[e] = ga; wbe[e] = b3[c] - m * ga;
    }
    const size_t pxbase = (size_t)b * HWSZ + (size_t)blockIdx.x * 256;
    double dot[5] = {0.0, 0.0, 0.0, 0.0, 0.0};
    for (int it = 0; it < 8; it++) {
        size_t idx = (pxbase + it * 32 + pxr) * 48 + c0;
        float rr[8];
        ld8(v + idx, rr);
        #pragma unroll
        for (int e = 0; e < 8; e++) rr[e] = fmaf(rr[e], wga[e], wbe[e]);
        st8(F + idx, rr);
        if (nf > 0) {
            float zz[8], gg[8];
            ld8(z + idx, zz);
            #pragma unroll
            for (int e = 0; e < 8; e++) gg[e] = rr[e] - zz[e];
            st8(G + idx, gg);
            #pragma unroll
            for (int i = 0; i < 5; i++) {
                if (i >= nf) continue;
                float d = 0.f;
                if (i == jslot) {
                    #pragma unroll
                    for (int e = 0; e < 8; e++) d = fmaf(gg[e], gg[e], d);
                } else {
                    float gi[8];
                    ld8(Gall + (size_t)i * SLOT + idx, gi);
                    #pragma unroll
                    for (int e = 0; e < 8; e++) d = fmaf(gg[e], gi[e], d);
                }
                dot[i] += (double)d;
            }
        }
    }
    if (nf > 0) {
        #pragma unroll
        for (int i = 0; i < 5; i++) {
            if (i >= nf) continue;
            #pragma unroll
            for (int off = 32; off > 0; off >>= 1) dot[i] += __shfl_down(dot[i], off);
        }
        int wv = tid >> 6;
        if ((tid & 63) == 0) {
            #pragma unroll
            for (int i = 0; i < 5; i++) if (i < nf) red[wv][i] = dot[i];
        }
        __syncthreads();
        if (tid == 0) {
            #pragma unroll
            for (int i = 0; i < 5; i++) {
                if (i >= nf) continue;
                double D = red[0][i] + red[1][i] + red[2][i];
                unsafeAtomicAdd(&gram[b * 25 + jslot * 5 + i], D);
                if (i != jslot) unsafeAtomicAdd(&gram[b * 25 + i * 5 + jslot], D);
            }
        }
    }
}

// ---------------- Anderson solve + xk ----------------

__global__ void solve_kernel(const double* __restrict__ gram, float* __restrict__ alpha, int n) {
    int b = threadIdx.x;
    if (b >= BB) return;
    const int m = n + 1;
    double A[6][7];
    for (int i = 0; i < m; i++)
        for (int jj = 0; jj <= m; jj++) A[i][jj] = 0.0;
    for (int i = 1; i < m; i++) { A[0][i] = 1.0; A[i][0] = 1.0; }
    for (int i = 1; i < m; i++)
        for (int jj = 1; jj < m; jj++)
            A[i][jj] = gram[b * 25 + (i - 1) * 5 + (jj - 1)] + ((i == jj) ? LAMV : 0.0);
    A[0][m] = 1.0;
    for (int col = 0; col < m; col++) {
        int piv = col; double best = fabs(A[col][col]);
        for (int rr = col + 1; rr < m; rr++) {
            double tv = fabs(A[rr][col]);
            if (tv > best) { best = tv; piv = rr; }
        }
        if (piv != col)
            for (int cc = col; cc <= m; cc++) {
                double tmp = A[col][cc]; A[col][cc] = A[piv][cc]; A[piv][cc] = tmp;
            }
        double invp = 1.0 / A[col][col];
        for (int cc = col; cc <= m; cc++) A[col][cc] *= invp;
        for (int rr = 0; rr < m; rr++) {
            if (rr == col) continue;
            double f = A[rr][col];
            if (f != 0.0)
                for (int cc = col; cc <= m; cc++) A[rr][cc] = fma(-f, A[col][cc], A[rr][cc]);
        }
    }
    for (int i = 0; i < n; i++) alpha[b * 5 + i] = (float)A[i + 1][m];
}

// xk = sum alpha_j F_j, looped 8x8 elems/thread; block 0 zeroes gram row/col jz
__global__ __launch_bounds__(256) void xk_kernel(
    const bf16_t* __restrict__ Fb, const float* __restrict__ alpha,
    bf16_t* __restrict__ zcur, int n, double* __restrict__ gram, int jz, int nf)
{
    if (blockIdx.x == 0 && threadIdx.x < 8 * nf) {
        int b = threadIdx.x / nf, i = threadIdx.x % nf;
        gram[b * 25 + jz * 5 + i] = 0.0;
        gram[b * 25 + i * 5 + jz] = 0.0;
    }
    const int b = blockIdx.x / 75;
    float al[5];
    #pragma unroll
    for (int j = 0; j < 5; j++) al[j] = (j < n) ? alpha[b * 5 + j] : 0.f;
    const size_t base = (size_t)blockIdx.x * 16384 + (size_t)threadIdx.x * 8;
    for (int it = 0; it < 8; it++) {
        size_t idx = base + (size_t)it * 2048;
        float s[8] = {0.f, 0.f, 0.f, 0.f, 0.f, 0.f, 0.f, 0.f};
        #pragma unroll
        for (int j = 0; j < 5; j++) {
            if (j < n) {
                float f[8];
                ld8(Fb + (size_t)j * SLOT + idx, f);
                #pragma unroll
                for (int e = 0; e < 8; e++) s[e] = fmaf(f[e], al[j], s[e]);
            }
        }
        st8(zcur + idx, s);
    }
}

// ---------------- final linear (NHWC bf16 in) ----------------
__global__ __launch_bounds__(512) void fc_kernel(
    const bf16_t* __restrict__ zf, const float* __restrict__ fw,
    const float* __restrict__ fb, float* __restrict__ out)
{
    __shared__ bf16_t row[9600];
    __shared__ float fwT[2000];
    int tid = threadIdx.x;
    int b = blockIdx.x >> 7, hh = blockIdx.x & 127;
    size_t base = (((size_t)b * HH + hh) * WW) * 48;
    for (int i = tid; i < 2400; i += 512)
        *(ushort4*)&row[i * 4] = *(const ushort4*)(zf + base + (size_t)i * 4);
    for (int i = tid; i < 2000; i += 512) fwT[i] = fw[i];
    __syncthreads();
    if (tid < 480) {
        int c = tid % 48, o = tid / 48;
        float acc = fb[o];
        #pragma unroll 4
        for (int w = 0; w < 200; w++)
            acc = fmaf(b2f(row[w * 48 + c]), fwT[o * 200 + w], acc);
        out[(((size_t)b * 48 + c) * HH + hh) * 10 + o] = acc;
    }
}

// ---------------- host ----------------

static inline int imin(int a, int b) { return a < b ? a : b; }

extern "C" void kernel_launch(void* const* d_in, const int* in_sizes, int n_in,
                              void* d_out, int out_size, void* d_ws, size_t ws_size,
                              hipStream_t stream)
{
    const float* x   = (const float*)d_in[0];
    const float* w0  = (const float*)d_in[1];
    const float* b0  = (const float*)d_in[2];
    const float* bng = (const float*)d_in[3];
    const float* bnb = (const float*)d_in[4];
    const float* w1  = (const float*)d_in[5];
    const float* w2  = (const float*)d_in[6];
    const float* g1  = (const float*)d_in[7];
    const float* be1 = (const float*)d_in[8];
    const float* g2  = (const float*)d_in[9];
    const float* be2 = (const float*)d_in[10];
    const float* g3  = (const float*)d_in[11];
    const float* be3 = (const float*)d_in[12];
    const float* fcw = (const float*)d_in[13];
    const float* fcb = (const float*)d_in[14];
    float* out = (float*)d_out;

    bf16_t* h    = (bf16_t*)d_ws;           // SLOT    (NHWC)
    bf16_t* zcur = h + (size_t)SLOT;        // SLOT
    bf16_t* y64  = zcur + (size_t)SLOT;     // Y64SZ
    bf16_t* Fb   = y64 + (size_t)Y64SZ;     // 5*SLOT
    bf16_t* Gb   = Fb + 5 * (size_t)SLOT;   // 5*SLOT
    double* dstats = (double*)((char*)d_ws + BIGELEMS * 2);  // 9696 dbl: BN 96 + 25*384
    double* gram   = dstats + 9696;                          // 200 dbl
    float*  alpha  = (float*)(gram + 200);                   // 40 f
    bf16_t* apk1   = (bf16_t*)(alpha + 40);                  // 27648
    bf16_t* apk2   = apk1 + 27648;                           // 36864
    float*  scratch = (float*)Gb;  // conv0 raw fp32 (G region dead at that point)

    const size_t need = BIGELEMS * 2 + 9696 * 8 + 200 * 8 + 40 * 4 + (27648 + 36864) * 2;
    if (ws_size < need) return;

    const dim3 blk(256);
    const int CHUNKS16 = SLOT * 2 / 16 / 256;  // 4800

    zero_kernel<<<(19792 + 255) / 256, blk, 0, stream>>>((float*)dstats, 19792);
    pack_kernel<<<108, blk, 0, stream>>>(w1, apk1, 48, 64, 27648);
    pack_kernel<<<144, blk, 0, stream>>>(w2, apk2, 64, 48, 36864);
    fill16_kernel<<<CHUNKS16, blk, 0, stream>>>((float4*)zcur);

    // h = BN(conv0(x)+b0) in NHWC bf16
    conv0_kernel<<<BB * HH, blk, 0, stream>>>(x, w0, b0, scratch);
    bn_stats_kernel<<<dim3(100, BB), dim3(192), 0, stream>>>(scratch, dstats);
    bn_apply_kernel<<<SLOT / 1024, blk, 0, stream>>>(scratch, h, bng, bnb, dstats);

    int call = 0;
    auto resnet = [&](const bf16_t* zin, bf16_t* Fdst, bf16_t* Gdst, int jslot, int nf) {
        double* ds = dstats + 96 + 384 * call;  // ds1 = +0, ds2 = +128, ds3 = +256
        call++;
        dim3 cg(7, 32, BB);
        conv_mfma_kernel<48, 52, 64, 66, 8, true, false, false><<<cg, blk, 0, stream>>>(
            zin, (const s8v*)apk1, nullptr, y64, ds, nullptr, nullptr, nullptr);
        conv_mfma_kernel<64, 68, 48, 50, 6, false, true, true><<<cg, blk, 0, stream>>>(
            y64, (const s8v*)apk2, h, Fdst, ds + 128, ds, g1, be1);
        add_relu_gn2_kernel<<<dim3(100, BB), dim3(192), 0, stream>>>(
            Fdst, zin, ds + 128, g2, be2, ds + 256);
        gn3_gram_kernel<<<dim3(100, BB), dim3(192), 0, stream>>>(
            Fdst, zin, Fdst, Gdst, ds + 256, g3, be3, Gb, jslot, nf, gram);
    };

    // slot 0: X=0, F0=f(0), G0=F0 (gram[0,0] accumulated in gn3)
    resnet(zcur, Fb, Gb, 0, 1);
    // slot 1: X=F0, F1=f(F0), G1=F1-F0
    copy16_kernel<<<CHUNKS16, blk, 0, stream>>>((float4*)zcur, (const float4*)Fb);
    resnet(zcur, Fb + (size_t)SLOT, Gb + (size_t)SLOT, 1, 2);

    for (int k = 2; k <= 24; k++) {
        int n = imin(k, 5);
        int j = k % 5;
        int nf = imin(k + 1, 5);
        solve_kernel<<<1, 64, 0, stream>>>(gram, alpha, n);
        xk_kernel<<<600, blk, 0, stream>>>(Fb, alpha, zcur, n, gram, j, nf);
        if (k < 24)   // reference computes Fv at k=24 but never uses it
            resnet(zcur, Fb + (size_t)j * SLOT, Gb + (size_t)j * SLOT, j, nf);
    }

    // z_star = zcur; one extra f application into F slot 0 (no G, no gram)
    resnet(zcur, Fb, nullptr, 0, 0);

    // final linear: NHWC [8,128,200,48] x fw[10,200] -> out [8,48,128,10]
    fc_kernel<<<BB * HH, dim3(512), 0, stream>>>(Fb, fcw, fcb, out);
}

// Round 9
// 5213.592 us; speedup vs baseline: 1.3975x; 1.0146x over previous
//
#include <hip/hip_runtime.h>

#define BB   8
#define HH   128
#define WW   200
#define HWSZ 25600
#define C48  48
#define C64  64
#define NGRP 8
#define EPSV 1e-5f
#define LAMV 1e-4
#define SLOT 9830400          // BB*C48*HWSZ elements (one z/F/G slot)
#define DPB  1228800          // C48*HWSZ per-batch flat dim
#define Y64SZ 13107200        // BB*C64*HWSZ
#define BIGELEMS 131072000ull // 12*SLOT + Y64SZ

typedef unsigned short bf16_t;
typedef __attribute__((ext_vector_type(4))) short s4v;
typedef __attribute__((ext_vector_type(8))) short s8v;
typedef __attribute__((ext_vector_type(16))) float f32x16;

__device__ inline float b2f(bf16_t b) { return __uint_as_float(((unsigned)b) << 16); }
__device__ inline bf16_t f2b(float f) {
    unsigned u = __float_as_uint(f);
    unsigned r = u + 0x7fffu + ((u >> 16) & 1u);
    return (bf16_t)(r >> 16);
}
__device__ inline float lo16(unsigned u) { return __uint_as_float(u << 16); }
__device__ inline float hi16(unsigned u) { return __uint_as_float(u & 0xffff0000u); }
__device__ inline unsigned pack2(float lo, float hi) {
    return ((unsigned)f2b(lo)) | (((unsigned)f2b(hi)) << 16);
}
__device__ inline float4 ld4(const bf16_t* p) {
    ushort4 u = *(const ushort4*)p;
    return make_float4(b2f(u.x), b2f(u.y), b2f(u.z), b2f(u.w));
}
__device__ inline void st4(bf16_t* p, float4 v) {
    ushort4 u; u.x = f2b(v.x); u.y = f2b(v.y); u.z = f2b(v.z); u.w = f2b(v.w);
    *(ushort4*)p = u;
}
// 8 bf16 <-> 8 floats via one 16B op
__device__ inline void ld8(const bf16_t* p, float* v) {
    uint4 u = *(const uint4*)p;
    v[0] = lo16(u.x); v[1] = hi16(u.x); v[2] = lo16(u.y); v[3] = hi16(u.y);
    v[4] = lo16(u.z); v[5] = hi16(u.z); v[6] = lo16(u.w); v[7] = hi16(u.w);
}
__device__ inline void st8(bf16_t* p, const float* v) {
    uint4 u;
    u.x = pack2(v[0], v[1]); u.y = pack2(v[2], v[3]);
    u.z = pack2(v[4], v[5]); u.w = pack2(v[6], v[7]);
    *(uint4*)p = u;
}

// (mean, invstd) from f64 sums at use site
__device__ inline void ms_from(const double* __restrict__ ds, int pair, double invcnt,
                               float& mean, float& inv) {
    double s = ds[2 * pair], q = ds[2 * pair + 1];
    double m = s * invcnt;
    double v = q * invcnt - m * m;
    mean = (float)m;
    inv = (float)(1.0 / sqrt(v + (double)EPSV));
}

// ---------------- utility ----------------

__global__ void zero_kernel(float* __restrict__ p, int n) {
    int i = blockIdx.x * 256 + threadIdx.x;
    if (i < n) p[i] = 0.f;
}
__global__ void fill16_kernel(float4* __restrict__ p) {
    float4 z; z.x = z.y = z.z = z.w = 0.f;
    p[(size_t)blockIdx.x * 256 + threadIdx.x] = z;
}
__global__ void copy16_kernel(float4* __restrict__ dst, const float4* __restrict__ src) {
    size_t i = (size_t)blockIdx.x * 256 + threadIdx.x;
    dst[i] = src[i];
}

// ---------------- weight packing: [kc][tap][mt][lane][8] bf16 ----------------
__global__ void pack_kernel(const float* __restrict__ w, bf16_t* __restrict__ apk,
                            int CIN, int CO_real, int total) {
    int idx = blockIdx.x * 256 + threadIdx.x;
    if (idx >= total) return;
    int j   = idx & 7;
    int l   = (idx >> 3) & 63;
    int mt  = (idx >> 9) & 1;
    int tap = (idx >> 10) % 9;
    int kc  = idx / 9216;
    int co = mt * 32 + (l & 31);
    int ci = kc * 16 + (l >> 5) * 8 + j;
    float v = (co < CO_real) ? w[((size_t)co * CIN + ci) * 9 + tap] : 0.f;
    apk[idx] = f2b(v);
}

// ---------------- conv0 (1->48): one (b,y) row per block, coalesced NHWC out ----------------
__global__ __launch_bounds__(256) void conv0_kernel(
    const float* __restrict__ x, const float* __restrict__ w0,
    const float* __restrict__ b0, float* __restrict__ out)
{
    __shared__ float xs[3 * 202];
    __shared__ float wt[480];
    const int tid = threadIdx.x;
    const int bI = blockIdx.x / HH, y = blockIdx.x % HH;
    for (int i = tid; i < 606; i += 256) {
        int r = i / 202, cc = i % 202;
        int gy = y + r - 1, gx = cc - 1;
        float v = 0.f;
        if ((unsigned)gy < (unsigned)HH && (unsigned)gx < (unsigned)WW)
            v = x[(size_t)bI * HWSZ + gy * WW + gx];
        xs[r * 202 + cc] = v;
    }
    for (int i = tid; i < 480; i += 256) wt[i] = (i < 432) ? w0[i] : b0[i - 432];
    __syncthreads();
    const size_t obase = (((size_t)bI * HH + y) * WW) * 48;
    for (int ch = tid; ch < 2400; ch += 256) {
        int px = (ch * 4) / 48, c0 = (ch * 4) % 48;
        float xv[3][3];
        #pragma unroll
        for (int r = 0; r < 3; r++)
            #pragma unroll
            for (int dx = 0; dx < 3; dx++)
                xv[r][dx] = xs[r * 202 + px + dx];
        float4 o;
        #pragma unroll
        for (int j = 0; j < 4; j++) {
            int c = c0 + j;
            float acc = wt[432 + c];
            #pragma unroll
            for (int r = 0; r < 3; r++)
                #pragma unroll
                for (int dx = 0; dx < 3; dx++)
                    acc = fmaf(xv[r][dx], wt[c * 9 + r * 3 + dx], acc);
            ((float*)&o)[j] = acc;
        }
        *(float4*)(out + obase + ch * 4) = o;
    }
}

// ---------------- channel-phased BN stats (fp32 src) ----------------
__global__ void bn_stats_kernel(const float* __restrict__ src, double* __restrict__ dst)
{
    __shared__ float ss[192], qq[192];
    const int tid = threadIdx.x;
    const int c = tid % 48, r = tid / 48;
    const int b = blockIdx.y;
    const size_t base = ((size_t)b * HWSZ + (size_t)blockIdx.x * 256) * 48 + c;
    float s = 0.f, q = 0.f;
    for (int p = r; p < 256; p += 4) {
        float v = src[base + (size_t)p * 48];
        s += v; q += v * v;
    }
    ss[tid] = s; qq[tid] = q;
    __syncthreads();
    if (tid < 48) {
        s = ss[tid] + ss[tid + 48] + ss[tid + 96] + ss[tid + 144];
        q = qq[tid] + qq[tid + 48] + qq[tid + 96] + qq[tid + 144];
        unsafeAtomicAdd(&dst[tid * 2],     (double)s);
        unsafeAtomicAdd(&dst[tid * 2 + 1], (double)q);
    }
}

// ---------------- BN apply: fp32 NHWC raw -> bf16 NHWC h ----------------
__global__ __launch_bounds__(256) void bn_apply_kernel(
    const float* __restrict__ src, bf16_t* __restrict__ dst,
    const float* __restrict__ gamma, const float* __restrict__ beta,
    const double* __restrict__ ds)
{
    __shared__ float gaT[48], beT[48];
    int tid = threadIdx.x;
    if (tid < 48) {
        float mean, inv; ms_from(ds, tid, 1.0 / 204800.0, mean, inv);
        float ga = gamma[tid] * inv;
        gaT[tid] = ga; beT[tid] = beta[tid] - mean * ga;
    }
    __syncthreads();
    size_t base = (size_t)blockIdx.x * 1024 + (size_t)tid * 4;
    int c0 = (int)(base % 48);
    float4 v = *(const float4*)(src + base);
    ushort4 o;
    o.x = f2b(fmaf(v.x, gaT[c0],     beT[c0]));
    o.y = f2b(fmaf(v.y, gaT[c0 + 1], beT[c0 + 1]));
    o.z = f2b(fmaf(v.z, gaT[c0 + 2], beT[c0 + 2]));
    o.w = f2b(fmaf(v.w, gaT[c0 + 3], beT[c0 + 3]));
    *(ushort4*)(dst + base) = o;
}

// ---------------- MFMA implicit-GEMM 3x3 conv: tap-outer / kc-inner main loop -------------
// grid (7 x-tiles of 32, 32 y-tiles of 4, 8 b); block 256 = 4 waves (one output row each).
// A-frags: per tap only 2*KC live (exactly-once global loads, L1-hot).
// B-frags: single aligned ds_read_b128 (CIPAD multiple of 8).
template<int CIN, int CIPAD, int CO, int OTS, int CG, bool RELU, bool ADDH, bool FOLDGN>
__global__ __launch_bounds__(256) void conv_mfma_kernel(
    const bf16_t* __restrict__ in, const s8v* __restrict__ apk,
    const bf16_t* __restrict__ hadd, bf16_t* __restrict__ out,
    double* __restrict__ dsOut,
    const double* __restrict__ dsPrev, const float* __restrict__ gPrev,
    const float* __restrict__ bPrev)
{
    constexpr int KC  = CIN / 16;
    constexpr int NCH = CIN / 4;
    const int tid  = threadIdx.x;
    const int lane = tid & 63;
    const int wv   = tid >> 6;
    const int x0 = blockIdx.x * 32;
    const int y0 = blockIdx.y * 4;
    const int b  = blockIdx.z;

    __shared__ __align__(16) bf16_t bt[6 * 34 * CIPAD];   // also reused as ot[128][OTS]
    __shared__ __align__(16) float gaT[FOLDGN ? CIN : 4];
    __shared__ __align__(16) float beT[FOLDGN ? CIN : 4];
    __shared__ float ss[256], qq[256];

    if (FOLDGN) {
        if (tid < CIN) {
            float mean, inv;
            ms_from(dsPrev, b * NGRP + tid / (CIN / NGRP), 1.0 / 204800.0, mean, inv);
            float ga = gPrev[tid] * inv;
            gaT[tid] = ga; beT[tid] = bPrev[tid] - mean * ga;
        }
        __syncthreads();
    }
    for (int i = tid; i < 6 * 34 * NCH; i += 256) {
        int ch = i % NCH, p = i / NCH;
        int r = p / 34, c = p - r * 34;
        int gy = y0 + r - 1, gx = x0 + c - 1;
        ushort4 v = make_ushort4(0, 0, 0, 0);
        if ((unsigned)gy < (unsigned)HH && (unsigned)gx < (unsigned)WW) {
            ushort4 raw = *(const ushort4*)(in + ((((size_t)b * HH + gy) * WW + gx) * CIN + ch * 4));
            if (FOLDGN) {
                float4 ga4 = *(const float4*)&gaT[ch * 4];
                float4 be4 = *(const float4*)&beT[ch * 4];
                v.x = f2b(fmaf(b2f(raw.x), ga4.x, be4.x));
                v.y = f2b(fmaf(b2f(raw.y), ga4.y, be4.y));
                v.z = f2b(fmaf(b2f(raw.z), ga4.z, be4.z));
                v.w = f2b(fmaf(b2f(raw.w), ga4.w, be4.w));
            } else v = raw;
        }
        *(ushort4*)(bt + p * CIPAD + ch * 4) = v;
    }
    __syncthreads();

    const int n = lane & 31, half = lane >> 5;
    f32x16 acc0, acc1;
    #pragma unroll
    for (int i = 0; i < 16; i++) { acc0[i] = 0.f; acc1[i] = 0.f; }

    // tap-outer, kc-inner: per tap exactly 2*KC A-frag loads (32 VGPRs max live)
    #pragma unroll
    for (int ky = 0; ky < 3; ky++)
    #pragma unroll
    for (int kx = 0; kx < 3; kx++) {
        const int tap = ky * 3 + kx;
        s8v af[2 * KC];
        #pragma unroll
        for (int kc = 0; kc < KC; kc++) {
            af[2 * kc]     = apk[(size_t)kc * 1152 + tap * 128 + lane];
            af[2 * kc + 1] = apk[(size_t)kc * 1152 + tap * 128 + 64 + lane];
        }
        const bf16_t* brow = bt + ((wv + ky) * 34 + n + kx) * CIPAD + half * 8;
        #pragma unroll
        for (int kc = 0; kc < KC; kc++) {
            s8v bfrag = *(const s8v*)(brow + kc * 16);
            acc0 = __builtin_amdgcn_mfma_f32_32x32x16_bf16(af[2 * kc],     bfrag, acc0, 0, 0, 0);
            acc1 = __builtin_amdgcn_mfma_f32_32x32x16_bf16(af[2 * kc + 1], bfrag, acc1, 0, 0, 0);
        }
    }
    __syncthreads();   // bt reads done; reuse as ot

    bf16_t* ot = bt;
    {
        const int pxl = wv * 32 + n;
        const bool pv = (x0 + n) < WW;
        #pragma unroll
        for (int g4 = 0; g4 < 4; g4++) {
            s4v pk0;
            #pragma unroll
            for (int jj = 0; jj < 4; jj++) {
                float v = acc0[g4 * 4 + jj];
                if (RELU) v = fmaxf(v, 0.f);
                pk0[jj] = (short)(pv ? f2b(v) : (bf16_t)0);
            }
            *(s4v*)&ot[pxl * OTS + g4 * 8 + 4 * half] = pk0;
            const int c1b = 32 + g4 * 8 + 4 * half;
            if (c1b + 3 < CO) {
                s4v pk1;
                #pragma unroll
                for (int jj = 0; jj < 4; jj++) {
                    float v = acc1[g4 * 4 + jj];
                    if (RELU) v = fmaxf(v, 0.f);
                    pk1[jj] = (short)(pv ? f2b(v) : (bf16_t)0);
                }
                *(s4v*)&ot[pxl * OTS + c1b] = pk1;
            }
        }
    }
    __syncthreads();
    {
        constexpr int NCH8 = 128 * CO / 8;
        for (int ch = tid; ch < NCH8; ch += 256) {
            int pxl = ch / (CO / 8);
            int co0 = (ch % (CO / 8)) * 8;
            int row = pxl >> 5, col = pxl & 31;
            int xx = x0 + col;
            if (xx < WW) {
                bf16_t* lp = &ot[pxl * OTS + co0];
                size_t ga = (((size_t)b * HH + y0 + row) * WW + xx) * CO + co0;
                if (ADDH) {
                    float4 h0 = ld4(hadd + ga), h1 = ld4(hadd + ga + 4);
                    float4 l0 = ld4(lp), l1 = ld4(lp + 4);
                    float4 v0 = make_float4(l0.x + h0.x, l0.y + h0.y, l0.z + h0.z, l0.w + h0.w);
                    float4 v1 = make_float4(l1.x + h1.x, l1.y + h1.y, l1.z + h1.z, l1.w + h1.w);
                    st4(out + ga, v0); st4(out + ga + 4, v1);
                    st4(lp, v0); st4(lp + 4, v1);
                } else {
                    *(ushort4*)(out + ga)     = *(ushort4*)lp;
                    *(ushort4*)(out + ga + 4) = *(ushort4*)(lp + 4);
                }
            }
        }
    }
    if (ADDH) __syncthreads();
    {
        constexpr int NPH = 256 / CO;
        const int c = tid % CO, rr = tid / CO;
        float s = 0.f, q = 0.f;
        if (rr < NPH) {
            for (int px = rr; px < 128; px += NPH) {
                float v = b2f(ot[px * OTS + c]);
                s += v; q += v * v;
            }
        }
        ss[tid] = s; qq[tid] = q;
        __syncthreads();
        if (tid < CO) {
            float S = ss[tid], Q = qq[tid];
            #pragma unroll
            for (int p = 1; p < NPH; p++) { S += ss[tid + p * CO]; Q += qq[tid + p * CO]; }
            ss[tid] = S; qq[tid] = Q;
        }
        __syncthreads();
        if (tid < NGRP) {
            float S = 0.f, Q = 0.f;
            #pragma unroll
            for (int j = 0; j < CG; j++) { S += ss[tid * CG + j]; Q += qq[tid * CG + j]; }
            unsafeAtomicAdd(&dsOut[((size_t)b * NGRP + tid) * 2],     (double)S);
            unsafeAtomicAdd(&dsOut[((size_t)b * NGRP + tid) * 2 + 1], (double)Q);
        }
    }
}

// ---------------- v = relu(z + gn2(u)) in place on u, looped + register group stats ----------
__global__ __launch_bounds__(192) void add_relu_gn2_kernel(
    bf16_t* __restrict__ u, const bf16_t* __restrict__ z,
    const double* __restrict__ ds2, const float* __restrict__ g2,
    const float* __restrict__ b2, double* __restrict__ ds3)
{
    __shared__ float sm[16];
    const int tid = threadIdx.x;
    const int c0 = 8 * (tid % 6), pxr = tid / 6;
    const int b = blockIdx.y;
    if (tid < 16) sm[tid] = 0.f;
    const int gA = c0 / 6;
    const int split = (gA + 1) * 6 - c0;
    float meanA, invA, meanB, invB;
    ms_from(ds2, b * NGRP + gA,     1.0 / 153600.0, meanA, invA);
    ms_from(ds2, b * NGRP + gA + 1, 1.0 / 153600.0, meanB, invB);
    float wga[8], wbe[8];
    #pragma unroll
    for (int e = 0; e < 8; e++) {
        int c = c0 + e;
        float m = (e < split) ? meanA : meanB, iv = (e < split) ? invA : invB;
        float ga = g2[c] * iv;
        wga[e] = ga; wbe[e] = b2[c] - m * ga;
    }
    __syncthreads();
    const size_t pxbase = (size_t)b * HWSZ + (size_t)blockIdx.x * 256;
    float sA = 0.f, qA = 0.f, sB = 0.f, qB = 0.f;
    for (int it = 0; it < 8; it++) {
        size_t idx = (pxbase + it * 32 + pxr) * 48 + c0;
        float uu[8], zz[8], vv[8];
        ld8(u + idx, uu); ld8(z + idx, zz);
        #pragma unroll
        for (int e = 0; e < 8; e++) {
            float v = fmaxf(fmaf(uu[e], wga[e], wbe[e]) + zz[e], 0.f);
            vv[e] = v;
            if (e < split) { sA += v; qA += v * v; } else { sB += v; qB += v * v; }
        }
        st8(u + idx, vv);
    }
    atomicAdd(&sm[2 * gA], sA);     atomicAdd(&sm[2 * gA + 1], qA);
    atomicAdd(&sm[2 * gA + 2], sB); atomicAdd(&sm[2 * gA + 3], qB);
    __syncthreads();
    if (tid < NGRP) {
        unsafeAtomicAdd(&ds3[(b * NGRP + tid) * 2],     (double)sm[tid * 2]);
        unsafeAtomicAdd(&ds3[(b * NGRP + tid) * 2 + 1], (double)sm[tid * 2 + 1]);
    }
}

// ---------------- gn3 apply + fused Gram row, looped (MLP) ----------------
__global__ __launch_bounds__(192) void gn3_gram_kernel(
    const bf16_t* __restrict__ v, const bf16_t* __restrict__ z,
    bf16_t* __restrict__ F, bf16_t* __restrict__ G,
    const double* __restrict__ ds3, const float* __restrict__ g3,
    const float* __restrict__ b3,
    const bf16_t* __restrict__ Gall, int jslot, int nf, double* __restrict__ gram)
{
    __shared__ double red[3][5];
    const int tid = threadIdx.x;
    const int c0 = 8 * (tid % 6), pxr = tid / 6;
    const int b = blockIdx.y;
    const int gA = c0 / 6;
    const int split = (gA + 1) * 6 - c0;
    float meanA, invA, meanB, invB;
    ms_from(ds3, b * NGRP + gA,     1.0 / 153600.0, meanA, invA);
    ms_from(ds3, b * NGRP + gA + 1, 1.0 / 153600.0, meanB, invB);
    float wga[8], wbe[8];
    #pragma unroll
    for (int e = 0; e < 8; e++) {
        int c = c0 + e;
        float m = (e < split) ? meanA : meanB, iv = (e < split) ? invA : invB;
        float ga = g3[c] * iv;
        wga[e] = ga; wbe[e] = b3[c] - m * ga;
    }
    const size_t pxbase = (size_t)b * HWSZ + (size_t)blockIdx.x * 256;
    double dot[5] = {0.0, 0.0, 0.0, 0.0, 0.0};
    for (int it = 0; it < 8; it++) {
        size_t idx = (pxbase + it * 32 + pxr) * 48 + c0;
        float rr[8];
        ld8(v + idx, rr);
        #pragma unroll
        for (int e = 0; e < 8; e++) rr[e] = fmaf(rr[e], wga[e], wbe[e]);
        st8(F + idx, rr);
        if (nf > 0) {
            float zz[8], gg[8];
            ld8(z + idx, zz);
            #pragma unroll
            for (int e = 0; e < 8; e++) gg[e] = rr[e] - zz[e];
            st8(G + idx, gg);
            #pragma unroll
            for (int i = 0; i < 5; i++) {
                if (i >= nf) continue;
                float d = 0.f;
                if (i == jslot) {
                    #pragma unroll
                    for (int e = 0; e < 8; e++) d = fmaf(gg[e], gg[e], d);
                } else {
                    float gi[8];
                    ld8(Gall + (size_t)i * SLOT + idx, gi);
                    #pragma unroll
                    for (int e = 0; e < 8; e++) d = fmaf(gg[e], gi[e], d);
                }
                dot[i] += (double)d;
            }
        }
    }
    if (nf > 0) {
        #pragma unroll
        for (int i = 0; i < 5; i++) {
            if (i >= nf) continue;
            #pragma unroll
            for (int off = 32; off > 0; off >>= 1) dot[i] += __shfl_down(dot[i], off);
        }
        int wv = tid >> 6;
        if ((tid & 63) == 0) {
            #pragma unroll
            for (int i = 0; i < 5; i++) if (i < nf) red[wv][i] = dot[i];
        }
        __syncthreads();
        if (tid == 0) {
            #pragma unroll
            for (int i = 0; i < 5; i++) {
                if (i >= nf) continue;
                double D = red[0][i] + red[1][i] + red[2][i];
                unsafeAtomicAdd(&gram[b * 25 + jslot * 5 + i], D);
                if (i != jslot) unsafeAtomicAdd(&gram[b * 25 + i * 5 + jslot], D);
            }
        }
    }
}

// ---------------- Anderson solve + xk ----------------

__global__ void solve_kernel(const double* __restrict__ gram, float* __restrict__ alpha, int n) {
    int b = threadIdx.x;
    if (b >= BB) return;
    const int m = n + 1;
    double A[6][7];
    for (int i = 0; i < m; i++)
        for (int jj = 0; jj <= m; jj++) A[i][jj] = 0.0;
    for (int i = 1; i < m; i++) { A[0][i] = 1.0; A[i][0] = 1.0; }
    for (int i = 1; i < m; i++)
        for (int jj = 1; jj < m; jj++)
            A[i][jj] = gram[b * 25 + (i - 1) * 5 + (jj - 1)] + ((i == jj) ? LAMV : 0.0);
    A[0][m] = 1.0;
    for (int col = 0; col < m; col++) {
        int piv = col; double best = fabs(A[col][col]);
        for (int rr = col + 1; rr < m; rr++) {
            double tv = fabs(A[rr][col]);
            if (tv > best) { best = tv; piv = rr; }
        }
        if (piv != col)
            for (int cc = col; cc <= m; cc++) {
                double tmp = A[col][cc]; A[col][cc] = A[piv][cc]; A[piv][cc] = tmp;
            }
        double invp = 1.0 / A[col][col];
        for (int cc = col; cc <= m; cc++) A[col][cc] *= invp;
        for (int rr = 0; rr < m; rr++) {
            if (rr == col) continue;
            double f = A[rr][col];
            if (f != 0.0)
                for (int cc = col; cc <= m; cc++) A[rr][cc] = fma(-f, A[col][cc], A[rr][cc]);
        }
    }
    for (int i = 0; i < n; i++) alpha[b * 5 + i] = (float)A[i + 1][m];
}

// xk = sum alpha_j F_j, looped 8x8 elems/thread; block 0 zeroes gram row/col jz
__global__ __launch_bounds__(256) void xk_kernel(
    const bf16_t* __restrict__ Fb, const float* __restrict__ alpha,
    bf16_t* __restrict__ zcur, int n, double* __restrict__ gram, int jz, int nf)
{
    if (blockIdx.x == 0 && threadIdx.x < 8 * nf) {
        int b = threadIdx.x / nf, i = threadIdx.x % nf;
        gram[b * 25 + jz * 5 + i] = 0.0;
        gram[b * 25 + i * 5 + jz] = 0.0;
    }
    const int b = blockIdx.x / 75;
    float al[5];
    #pragma unroll
    for (int j = 0; j < 5; j++) al[j] = (j < n) ? alpha[b * 5 + j] : 0.f;
    const size_t base = (size_t)blockIdx.x * 16384 + (size_t)threadIdx.x * 8;
    for (int it = 0; it < 8; it++) {
        size_t idx = base + (size_t)it * 2048;
        float s[8] = {0.f, 0.f, 0.f, 0.f, 0.f, 0.f, 0.f, 0.f};
        #pragma unroll
        for (int j = 0; j < 5; j++) {
            if (j < n) {
                float f[8];
                ld8(Fb + (size_t)j * SLOT + idx, f);
                #pragma unroll
                for (int e = 0; e < 8; e++) s[e] = fmaf(f[e], al[j], s[e]);
            }
        }
        st8(zcur + idx, s);
    }
}

// ---------------- final linear (NHWC bf16 in) ----------------
__global__ __launch_bounds__(512) void fc_kernel(
    const bf16_t* __restrict__ zf, const float* __restrict__ fw,
    const float* __restrict__ fb, float* __restrict__ out)
{
    __shared__ bf16_t row[9600];
    __shared__ float fwT[2000];
    int tid = threadIdx.x;
    int b = blockIdx.x >> 7, hh = blockIdx.x & 127;
    size_t base = (((size_t)b * HH + hh) * WW) * 48;
    for (int i = tid; i < 2400; i += 512)
        *(ushort4*)&row[i * 4] = *(const ushort4*)(zf + base + (size_t)i * 4);
    for (int i = tid; i < 2000; i += 512) fwT[i] = fw[i];
    __syncthreads();
    if (tid < 480) {
        int c = tid % 48, o = tid / 48;
        float acc = fb[o];
        #pragma unroll 4
        for (int w = 0; w < 200; w++)
            acc = fmaf(b2f(row[w * 48 + c]), fwT[o * 200 + w], acc);
        out[(((size_t)b * 48 + c) * HH + hh) * 10 + o] = acc;
    }
}

// ---------------- host ----------------

static inline int imin(int a, int b) { return a < b ? a : b; }

extern "C" void kernel_launch(void* const* d_in, const int* in_sizes, int n_in,
                              void* d_out, int out_size, void* d_ws, size_t ws_size,
                              hipStream_t stream)
{
    const float* x   = (const float*)d_in[0];
    const float* w0  = (const float*)d_in[1];
    const float* b0  = (const float*)d_in[2];
    const float* bng = (const float*)d_in[3];
    const float* bnb = (const float*)d_in[4];
    const float* w1  = (const float*)d_in[5];
    const float* w2  = (const float*)d_in[6];
    const float* g1  = (const float*)d_in[7];
    const float* be1 = (const float*)d_in[8];
    const float* g2  = (const float*)d_in[9];
    const float* be2 = (const float*)d_in[10];
    const float* g3  = (const float*)d_in[11];
    const float* be3 = (const float*)d_in[12];
    const float* fcw = (const float*)d_in[13];
    const float* fcb = (const float*)d_in[14];
    float* out = (float*)d_out;

    bf16_t* h    = (bf16_t*)d_ws;           // SLOT    (NHWC)
    bf16_t* zcur = h + (size_t)SLOT;        // SLOT
    bf16_t* y64  = zcur + (size_t)SLOT;     // Y64SZ
    bf16_t* Fb   = y64 + (size_t)Y64SZ;     // 5*SLOT
    bf16_t* Gb   = Fb + 5 * (size_t)SLOT;   // 5*SLOT
    double* dstats = (double*)((char*)d_ws + BIGELEMS * 2);  // 9696 dbl: BN 96 + 25*384
    double* gram   = dstats + 9696;                          // 200 dbl
    float*  alpha  = (float*)(gram + 200);                   // 40 f
    bf16_t* apk1   = (bf16_t*)(alpha + 40);                  // 27648
    bf16_t* apk2   = apk1 + 27648;                           // 36864
    float*  scratch = (float*)Gb;  // conv0 raw fp32 (G region dead at that point)

    const size_t need = BIGELEMS * 2 + 9696 * 8 + 200 * 8 + 40 * 4 + (27648 + 36864) * 2;
    if (ws_size < need) return;

    const dim3 blk(256);
    const int CHUNKS16 = SLOT * 2 / 16 / 256;  // 4800

    zero_kernel<<<(19792 + 255) / 256, blk, 0, stream>>>((float*)dstats, 19792);
    pack_kernel<<<108, blk, 0, stream>>>(w1, apk1, 48, 64, 27648);
    pack_kernel<<<144, blk, 0, stream>>>(w2, apk2, 64, 48, 36864);
    fill16_kernel<<<CHUNKS16, blk, 0, stream>>>((float4*)zcur);

    // h = BN(conv0(x)+b0) in NHWC bf16
    conv0_kernel<<<BB * HH, blk, 0, stream>>>(x, w0, b0, scratch);
    bn_stats_kernel<<<dim3(100, BB), dim3(192), 0, stream>>>(scratch, dstats);
    bn_apply_kernel<<<SLOT / 1024, blk, 0, stream>>>(scratch, h, bng, bnb, dstats);

    int call = 0;
    auto resnet = [&](const bf16_t* zin, bf16_t* Fdst, bf16_t* Gdst, int jslot, int nf) {
        double* ds = dstats + 96 + 384 * call;  // ds1 = +0, ds2 = +128, ds3 = +256
        call++;
        dim3 cg(7, 32, BB);
        conv_mfma_kernel<48, 56, 64, 66, 8, true, false, false><<<cg, blk, 0, stream>>>(
            zin, (const s8v*)apk1, nullptr, y64, ds, nullptr, nullptr, nullptr);
        conv_mfma_kernel<64, 72, 48, 50, 6, false, true, true><<<cg, blk, 0, stream>>>(
            y64, (const s8v*)apk2, h, Fdst, ds + 128, ds, g1, be1);
        add_relu_gn2_kernel<<<dim3(100, BB), dim3(192), 0, stream>>>(
            Fdst, zin, ds + 128, g2, be2, ds + 256);
        gn3_gram_kernel<<<dim3(100, BB), dim3(192), 0, stream>>>(
            Fdst, zin, Fdst, Gdst, ds + 256, g3, be3, Gb, jslot, nf, gram);
    };

    // slot 0: X=0, F0=f(0), G0=F0 (gram[0,0] accumulated in gn3)
    resnet(zcur, Fb, Gb, 0, 1);
    // slot 1: X=F0, F1=f(F0), G1=F1-F0
    copy16_kernel<<<CHUNKS16, blk, 0, stream>>>((float4*)zcur, (const float4*)Fb);
    resnet(zcur, Fb + (size_t)SLOT, Gb + (size_t)SLOT, 1, 2);

    for (int k = 2; k <= 24; k++) {
        int n = imin(k, 5);
        int j = k % 5;
        int nf = imin(k + 1, 5);
        solve_kernel<<<1, 64, 0, stream>>>(gram, alpha, n);
        xk_kernel<<<600, blk, 0, stream>>>(Fb, alpha, zcur, n, gram, j, nf);
        if (k < 24)   // reference computes Fv at k=24 but never uses it
            resnet(zcur, Fb + (size_t)j * SLOT, Gb + (size_t)j * SLOT, j, nf);
    }

    // z_star = zcur; one extra f application into F slot 0 (no G, no gram)
    resnet(zcur, Fb, nullptr, 0, 0);

    // final linear: NHWC [8,128,200,48] x fw[10,200] -> out [8,48,128,10]
    fc_kernel<<<BB * HH, dim3(512), 0, stream>>>(Fb, fcw, fcb, out);
}

// Round 12
// 5076.773 us; speedup vs baseline: 1.4352x; 1.0269x over previous
//
#include <hip/hip_runtime.h>

#define BB   8
#define HH   128
#define WW   200
#define HWSZ 25600
#define C48  48
#define C64  64
#define NGRP 8
#define EPSV 1e-5f
#define LAMV 1e-4
#define SLOT 9830400          // BB*C48*HWSZ elements (one z/F/G slot)
#define DPB  1228800          // C48*HWSZ per-batch flat dim
#define Y64SZ 13107200        // BB*C64*HWSZ
#define BIGELEMS 131072000ull // 12*SLOT + Y64SZ

typedef unsigned short bf16_t;
typedef __attribute__((ext_vector_type(4))) short s4v;
typedef __attribute__((ext_vector_type(8))) short s8v;
typedef __attribute__((ext_vector_type(16))) float f32x16;

__device__ inline float b2f(bf16_t b) { return __uint_as_float(((unsigned)b) << 16); }
__device__ inline bf16_t f2b(float f) {
    unsigned u = __float_as_uint(f);
    unsigned r = u + 0x7fffu + ((u >> 16) & 1u);
    return (bf16_t)(r >> 16);
}
__device__ inline float lo16(unsigned u) { return __uint_as_float(u << 16); }
__device__ inline float hi16(unsigned u) { return __uint_as_float(u & 0xffff0000u); }
__device__ inline unsigned pack2(float lo, float hi) {
    return ((unsigned)f2b(lo)) | (((unsigned)f2b(hi)) << 16);
}
__device__ inline float4 ld4(const bf16_t* p) {
    ushort4 u = *(const ushort4*)p;
    return make_float4(b2f(u.x), b2f(u.y), b2f(u.z), b2f(u.w));
}
__device__ inline void st4(bf16_t* p, float4 v) {
    ushort4 u; u.x = f2b(v.x); u.y = f2b(v.y); u.z = f2b(v.z); u.w = f2b(v.w);
    *(ushort4*)p = u;
}
// 8 bf16 <-> 8 floats via one 16B op
__device__ inline void ld8(const bf16_t* p, float* v) {
    uint4 u = *(const uint4*)p;
    v[0] = lo16(u.x); v[1] = hi16(u.x); v[2] = lo16(u.y); v[3] = hi16(u.y);
    v[4] = lo16(u.z); v[5] = hi16(u.z); v[6] = lo16(u.w); v[7] = hi16(u.w);
}
__device__ inline void st8(bf16_t* p, const float* v) {
    uint4 u;
    u.x = pack2(v[0], v[1]); u.y = pack2(v[2], v[3]);
    u.z = pack2(v[4], v[5]); u.w = pack2(v[6], v[7]);
    *(uint4*)p = u;
}

// (mean, invstd) from f64 sums at use site
__device__ inline void ms_from(const double* __restrict__ ds, int pair, double invcnt,
                               float& mean, float& inv) {
    double s = ds[2 * pair], q = ds[2 * pair + 1];
    double m = s * invcnt;
    double v = q * invcnt - m * m;
    mean = (float)m;
    inv = (float)(1.0 / sqrt(v + (double)EPSV));
}

// ---------------- utility ----------------

__global__ void zero_kernel(float* __restrict__ p, int n) {
    int i = blockIdx.x * 256 + threadIdx.x;
    if (i < n) p[i] = 0.f;
}
__global__ void fill16_kernel(float4* __restrict__ p) {
    float4 z; z.x = z.y = z.z = z.w = 0.f;
    p[(size_t)blockIdx.x * 256 + threadIdx.x] = z;
}
__global__ void copy16_kernel(float4* __restrict__ dst, const float4* __restrict__ src) {
    size_t i = (size_t)blockIdx.x * 256 + threadIdx.x;
    dst[i] = src[i];
}

// ---------------- weight packing: [kc][tap][mt][lane][8] bf16 ----------------
__global__ void pack_kernel(const float* __restrict__ w, bf16_t* __restrict__ apk,
                            int CIN, int CO_real, int total) {
    int idx = blockIdx.x * 256 + threadIdx.x;
    if (idx >= total) return;
    int j   = idx & 7;
    int l   = (idx >> 3) & 63;
    int mt  = (idx >> 9) & 1;
    int tap = (idx >> 10) % 9;
    int kc  = idx / 9216;
    int co = mt * 32 + (l & 31);
    int ci = kc * 16 + (l >> 5) * 8 + j;
    float v = (co < CO_real) ? w[((size_t)co * CIN + ci) * 9 + tap] : 0.f;
    apk[idx] = f2b(v);
}

// ---------------- conv0 (1->48): one (b,y) row per block, coalesced NHWC out ----------------
__global__ __launch_bounds__(256) void conv0_kernel(
    const float* __restrict__ x, const float* __restrict__ w0,
    const float* __restrict__ b0, float* __restrict__ out)
{
    __shared__ float xs[3 * 202];
    __shared__ float wt[480];
    const int tid = threadIdx.x;
    const int bI = blockIdx.x / HH, y = blockIdx.x % HH;
    for (int i = tid; i < 606; i += 256) {
        int r = i / 202, cc = i % 202;
        int gy = y + r - 1, gx = cc - 1;
        float v = 0.f;
        if ((unsigned)gy < (unsigned)HH && (unsigned)gx < (unsigned)WW)
            v = x[(size_t)bI * HWSZ + gy * WW + gx];
        xs[r * 202 + cc] = v;
    }
    for (int i = tid; i < 480; i += 256) wt[i] = (i < 432) ? w0[i] : b0[i - 432];
    __syncthreads();
    const size_t obase = (((size_t)bI * HH + y) * WW) * 48;
    for (int ch = tid; ch < 2400; ch += 256) {
        int px = (ch * 4) / 48, c0 = (ch * 4) % 48;
        float xv[3][3];
        #pragma unroll
        for (int r = 0; r < 3; r++)
            #pragma unroll
            for (int dx = 0; dx < 3; dx++)
                xv[r][dx] = xs[r * 202 + px + dx];
        float4 o;
        #pragma unroll
        for (int j = 0; j < 4; j++) {
            int c = c0 + j;
            float acc = wt[432 + c];
            #pragma unroll
            for (int r = 0; r < 3; r++)
                #pragma unroll
                for (int dx = 0; dx < 3; dx++)
                    acc = fmaf(xv[r][dx], wt[c * 9 + r * 3 + dx], acc);
            ((float*)&o)[j] = acc;
        }
        *(float4*)(out + obase + ch * 4) = o;
    }
}

// ---------------- channel-phased BN stats (fp32 src) ----------------
__global__ void bn_stats_kernel(const float* __restrict__ src, double* __restrict__ dst)
{
    __shared__ float ss[192], qq[192];
    const int tid = threadIdx.x;
    const int c = tid % 48, r = tid / 48;
    const int b = blockIdx.y;
    const size_t base = ((size_t)b * HWSZ + (size_t)blockIdx.x * 256) * 48 + c;
    float s = 0.f, q = 0.f;
    for (int p = r; p < 256; p += 4) {
        float v = src[base + (size_t)p * 48];
        s += v; q += v * v;
    }
    ss[tid] = s; qq[tid] = q;
    __syncthreads();
    if (tid < 48) {
        s = ss[tid] + ss[tid + 48] + ss[tid + 96] + ss[tid + 144];
        q = qq[tid] + qq[tid + 48] + qq[tid + 96] + qq[tid + 144];
        unsafeAtomicAdd(&dst[tid * 2],     (double)s);
        unsafeAtomicAdd(&dst[tid * 2 + 1], (double)q);
    }
}

// ---------------- BN apply: fp32 NHWC raw -> bf16 NHWC h ----------------
__global__ __launch_bounds__(256) void bn_apply_kernel(
    const float* __restrict__ src, bf16_t* __restrict__ dst,
    const float* __restrict__ gamma, const float* __restrict__ beta,
    const double* __restrict__ ds)
{
    __shared__ float gaT[48], beT[48];
    int tid = threadIdx.x;
    if (tid < 48) {
        float mean, inv; ms_from(ds, tid, 1.0 / 204800.0, mean, inv);
        float ga = gamma[tid] * inv;
        gaT[tid] = ga; beT[tid] = beta[tid] - mean * ga;
    }
    __syncthreads();
    size_t base = (size_t)blockIdx.x * 1024 + (size_t)tid * 4;
    int c0 = (int)(base % 48);
    float4 v = *(const float4*)(src + base);
    ushort4 o;
    o.x = f2b(fmaf(v.x, gaT[c0],     beT[c0]));
    o.y = f2b(fmaf(v.y, gaT[c0 + 1], beT[c0 + 1]));
    o.z = f2b(fmaf(v.z, gaT[c0 + 2], beT[c0 + 2]));
    o.w = f2b(fmaf(v.w, gaT[c0 + 3], beT[c0 + 3]));
    *(ushort4*)(dst + base) = o;
}

// ---------------- MFMA implicit-GEMM 3x3 conv: 8-wave tall blocks -------------
// grid (7 x-tiles of 32, 16 y-groups of 8, 8 b); block 512 = 8 waves (one output row each).
// Identical phase structure to the round-8 passing kernel (stage-all -> MFMA -> epilogue);
// only the tile height changed: 10 input rows staged, 8 output rows, 256 output px.
template<int CIN, int CIPAD, int CO, int OTS, int CG, bool RELU, bool ADDH, bool FOLDGN>
__global__ __launch_bounds__(512) void conv_mfma_kernel(
    const bf16_t* __restrict__ in, const s8v* __restrict__ apk,
    const bf16_t* __restrict__ hadd, bf16_t* __restrict__ out,
    double* __restrict__ dsOut,
    const double* __restrict__ dsPrev, const float* __restrict__ gPrev,
    const float* __restrict__ bPrev)
{
    constexpr int KC  = CIN / 16;
    constexpr int NCH = CIN / 4;
    const int tid  = threadIdx.x;
    const int lane = tid & 63;
    const int wv   = tid >> 6;          // 0..7 = output row within block
    const int x0 = blockIdx.x * 32;
    const int y0 = blockIdx.y * 8;
    const int b  = blockIdx.z;

    __shared__ __align__(16) bf16_t bt[10 * 34 * CIPAD];  // reused as ot[256][OTS]
    __shared__ __align__(16) float gaT[FOLDGN ? CIN : 4];
    __shared__ __align__(16) float beT[FOLDGN ? CIN : 4];
    __shared__ float ss[512], qq[512];

    if (FOLDGN) {
        if (tid < CIN) {
            float mean, inv;
            ms_from(dsPrev, b * NGRP + tid / (CIN / NGRP), 1.0 / 204800.0, mean, inv);
            float ga = gPrev[tid] * inv;
            gaT[tid] = ga; beT[tid] = bPrev[tid] - mean * ga;
        }
        __syncthreads();
    }
    // stage 10 input rows: gy = y0-1 .. y0+8
    for (int i = tid; i < 10 * 34 * NCH; i += 512) {
        int ch = i % NCH, p = i / NCH;
        int r = p / 34, c = p - r * 34;
        int gy = y0 + r - 1, gx = x0 + c - 1;
        ushort4 v = make_ushort4(0, 0, 0, 0);
        if ((unsigned)gy < (unsigned)HH && (unsigned)gx < (unsigned)WW) {
            ushort4 raw = *(const ushort4*)(in + ((((size_t)b * HH + gy) * WW + gx) * CIN + ch * 4));
            if (FOLDGN) {
                float4 ga4 = *(const float4*)&gaT[ch * 4];
                float4 be4 = *(const float4*)&beT[ch * 4];
                v.x = f2b(fmaf(b2f(raw.x), ga4.x, be4.x));
                v.y = f2b(fmaf(b2f(raw.y), ga4.y, be4.y));
                v.z = f2b(fmaf(b2f(raw.z), ga4.z, be4.z));
                v.w = f2b(fmaf(b2f(raw.w), ga4.w, be4.w));
            } else v = raw;
        }
        *(ushort4*)(bt + p * CIPAD + ch * 4) = v;
    }
    __syncthreads();

    const int n = lane & 31, half = lane >> 5;
    f32x16 acc0, acc1;
    #pragma unroll
    for (int i = 0; i < 16; i++) { acc0[i] = 0.f; acc1[i] = 0.f; }

    // tap-outer, kc-inner (round-8 structure; local row = wv+ky, wv now 0..7)
    #pragma unroll
    for (int ky = 0; ky < 3; ky++)
    #pragma unroll
    for (int kx = 0; kx < 3; kx++) {
        const int tap = ky * 3 + kx;
        s8v af[2 * KC];
        #pragma unroll
        for (int kc = 0; kc < KC; kc++) {
            af[2 * kc]     = apk[(size_t)kc * 1152 + tap * 128 + lane];
            af[2 * kc + 1] = apk[(size_t)kc * 1152 + tap * 128 + 64 + lane];
        }
        const bf16_t* brow = bt + ((wv + ky) * 34 + n + kx) * CIPAD + half * 8;
        #pragma unroll
        for (int kc = 0; kc < KC; kc++) {
            s8v bfrag = *(const s8v*)(brow + kc * 16);
            acc0 = __builtin_amdgcn_mfma_f32_32x32x16_bf16(af[2 * kc],     bfrag, acc0, 0, 0, 0);
            acc1 = __builtin_amdgcn_mfma_f32_32x32x16_bf16(af[2 * kc + 1], bfrag, acc1, 0, 0, 0);
        }
    }
    __syncthreads();   // bt reads done; reuse as ot

    bf16_t* ot = bt;
    {
        const int pxl = wv * 32 + n;   // 0..255
        const bool pv = (x0 + n) < WW;
        #pragma unroll
        for (int g4 = 0; g4 < 4; g4++) {
            s4v pk0;
            #pragma unroll
            for (int jj = 0; jj < 4; jj++) {
                float v = acc0[g4 * 4 + jj];
                if (RELU) v = fmaxf(v, 0.f);
                pk0[jj] = (short)(pv ? f2b(v) : (bf16_t)0);
            }
            *(s4v*)&ot[pxl * OTS + g4 * 8 + 4 * half] = pk0;
            const int c1b = 32 + g4 * 8 + 4 * half;
            if (c1b + 3 < CO) {
                s4v pk1;
                #pragma unroll
                for (int jj = 0; jj < 4; jj++) {
                    float v = acc1[g4 * 4 + jj];
                    if (RELU) v = fmaxf(v, 0.f);
                    pk1[jj] = (short)(pv ? f2b(v) : (bf16_t)0);
                }
                *(s4v*)&ot[pxl * OTS + c1b] = pk1;
            }
        }
    }
    __syncthreads();
    {
        constexpr int NCH8 = 256 * CO / 8;
        for (int ch = tid; ch < NCH8; ch += 512) {
            int pxl = ch / (CO / 8);
            int co0 = (ch % (CO / 8)) * 8;
            int row = pxl >> 5, col = pxl & 31;
            int xx = x0 + col;
            if (xx < WW) {
                bf16_t* lp = &ot[pxl * OTS + co0];
                size_t ga = (((size_t)b * HH + y0 + row) * WW + xx) * CO + co0;
                if (ADDH) {
                    float4 h0 = ld4(hadd + ga), h1 = ld4(hadd + ga + 4);
                    float4 l0 = ld4(lp), l1 = ld4(lp + 4);
                    float4 v0 = make_float4(l0.x + h0.x, l0.y + h0.y, l0.z + h0.z, l0.w + h0.w);
                    float4 v1 = make_float4(l1.x + h1.x, l1.y + h1.y, l1.z + h1.z, l1.w + h1.w);
                    st4(out + ga, v0); st4(out + ga + 4, v1);
                    st4(lp, v0); st4(lp + 4, v1);
                } else {
                    *(ushort4*)(out + ga)     = *(ushort4*)lp;
                    *(ushort4*)(out + ga + 4) = *(ushort4*)(lp + 4);
                }
            }
        }
    }
    if (ADDH) __syncthreads();
    {
        constexpr int NPH = 512 / CO;
        const int c = tid % CO, rr = tid / CO;
        float s = 0.f, q = 0.f;
        if (rr < NPH) {
            for (int px = rr; px < 256; px += NPH) {
                float v = b2f(ot[px * OTS + c]);
                s += v; q += v * v;
            }
        }
        ss[tid] = s; qq[tid] = q;
        __syncthreads();
        if (tid < CO) {
            float S = ss[tid], Q = qq[tid];
            #pragma unroll
            for (int p = 1; p < NPH; p++) { S += ss[tid + p * CO]; Q += qq[tid + p * CO]; }
            ss[tid] = S; qq[tid] = Q;
        }
        __syncthreads();
        if (tid < NGRP) {
            float S = 0.f, Q = 0.f;
            #pragma unroll
            for (int j = 0; j < CG; j++) { S += ss[tid * CG + j]; Q += qq[tid * CG + j]; }
            unsafeAtomicAdd(&dsOut[((size_t)b * NGRP + tid) * 2],     (double)S);
            unsafeAtomicAdd(&dsOut[((size_t)b * NGRP + tid) * 2 + 1], (double)Q);
        }
    }
}

// ---------------- v = relu(z + gn2(u)) in place on u, looped + register group stats ----------
__global__ __launch_bounds__(192) void add_relu_gn2_kernel(
    bf16_t* __restrict__ u, const bf16_t* __restrict__ z,
    const double* __restrict__ ds2, const float* __restrict__ g2,
    const float* __restrict__ b2, double* __restrict__ ds3)
{
    __shared__ float sm[16];
    const int tid = threadIdx.x;
    const int c0 = 8 * (tid % 6), pxr = tid / 6;
    const int b = blockIdx.y;
    if (tid < 16) sm[tid] = 0.f;
    const int gA = c0 / 6;
    const int split = (gA + 1) * 6 - c0;
    float meanA, invA, meanB, invB;
    ms_from(ds2, b * NGRP + gA,     1.0 / 153600.0, meanA, invA);
    ms_from(ds2, b * NGRP + gA + 1, 1.0 / 153600.0, meanB, invB);
    float wga[8], wbe[8];
    #pragma unroll
    for (int e = 0; e < 8; e++) {
        int c = c0 + e;
        float m = (e < split) ? meanA : meanB, iv = (e < split) ? invA : invB;
        float ga = g2[c] * iv;
        wga[e] = ga; wbe[e] = b2[c] - m * ga;
    }
    __syncthreads();
    const size_t pxbase = (size_t)b * HWSZ + (size_t)blockIdx.x * 256;
    float sA = 0.f, qA = 0.f, sB = 0.f, qB = 0.f;
    for (int it = 0; it < 8; it++) {
        size_t idx = (pxbase + it * 32 + pxr) * 48 + c0;
        float uu[8], zz[8], vv[8];
        ld8(u + idx, uu); ld8(z + idx, zz);
        #pragma unroll
        for (int e = 0; e < 8; e++) {
            float v = fmaxf(fmaf(uu[e], wga[e], wbe[e]) + zz[e], 0.f);
            vv[e] = v;
            if (e < split) { sA += v; qA += v * v; } else { sB += v; qB += v * v; }
        }
        st8(u + idx, vv);
    }
    atomicAdd(&sm[2 * gA], sA);     atomicAdd(&sm[2 * gA + 1], qA);
    atomicAdd(&sm[2 * gA + 2], sB); atomicAdd(&sm[2 * gA + 3], qB);
    __syncthreads();
    if (tid < NGRP) {
        unsafeAtomicAdd(&ds3[(b * NGRP + tid) * 2],     (double)sm[tid * 2]);
        unsafeAtomicAdd(&ds3[(b * NGRP + tid) * 2 + 1], (double)sm[tid * 2 + 1]);
    }
}

// ---------------- gn3 apply + fused Gram row, looped (MLP) ----------------
__global__ __launch_bounds__(192) void gn3_gram_kernel(
    const bf16_t* __restrict__ v, const bf16_t* __restrict__ z,
    bf16_t* __restrict__ F, bf16_t* __restrict__ G,
    const double* __restrict__ ds3, const float* __restrict__ g3,
    const float* __restrict__ b3,
    const bf16_t* __restrict__ Gall, int jslot, int nf, double* __restrict__ gram)
{
    __shared__ double red[3][5];
    const int tid = threadIdx.x;
    const int c0 = 8 * (tid % 6), pxr = tid / 6;
    const int b = blockIdx.y;
    const int gA = c0 / 6;
    const int split = (gA + 1) * 6 - c0;
    float meanA, invA, meanB, invB;
    ms_from(ds3, b * NGRP + gA,     1.0 / 153600.0, meanA, invA);
    ms_from(ds3, b * NGRP + gA + 1, 1.0 / 153600.0, meanB, invB);
    float wga[8], wbe[8];
    #pragma unroll
    for (int e = 0; e < 8; e++) {
        int c = c0 + e;
        float m = (e < split) ? meanA : meanB, iv = (e < split) ? invA : invB;
        float ga = g3[c] * iv;
        wga[e] = ga; wbe[e] = b3[c] - m * ga;
    }
    const size_t pxbase = (size_t)b * HWSZ + (size_t)blockIdx.x * 256;
    double dot[5] = {0.0, 0.0, 0.0, 0.0, 0.0};
    for (int it = 0; it < 8; it++) {
        size_t idx = (pxbase + it * 32 + pxr) * 48 + c0;
        float rr[8];
        ld8(v + idx, rr);
        #pragma unroll
        for (int e = 0; e < 8; e++) rr[e] = fmaf(rr[e], wga[e], wbe[e]);
        st8(F + idx, rr);
        if (nf > 0) {
            float zz[8], gg[8];
            ld8(z + idx, zz);
            #pragma unroll
            for (int e = 0; e < 8; e++) gg[e] = rr[e] - zz[e];
            st8(G + idx, gg);
            #pragma unroll
            for (int i = 0; i < 5; i++) {
                if (i >= nf) continue;
                float d = 0.f;
                if (i == jslot) {
                    #pragma unroll
                    for (int e = 0; e < 8; e++) d = fmaf(gg[e], gg[e], d);
                } else {
                    float gi[8];
                    ld8(Gall + (size_t)i * SLOT + idx, gi);
                    #pragma unroll
                    for (int e = 0; e < 8; e++) d = fmaf(gg[e], gi[e], d);
                }
                dot[i] += (double)d;
            }
        }
    }
    if (nf > 0) {
        #pragma unroll
        for (int i = 0; i < 5; i++) {
            if (i >= nf) continue;
            #pragma unroll
            for (int off = 32; off > 0; off >>= 1) dot[i] += __shfl_down(dot[i], off);
        }
        int wv = tid >> 6;
        if ((tid & 63) == 0) {
            #pragma unroll
            for (int i = 0; i < 5; i++) if (i < nf) red[wv][i] = dot[i];
        }
        __syncthreads();
        if (tid == 0) {
            #pragma unroll
            for (int i = 0; i < 5; i++) {
                if (i >= nf) continue;
                double D = red[0][i] + red[1][i] + red[2][i];
                unsafeAtomicAdd(&gram[b * 25 + jslot * 5 + i], D);
                if (i != jslot) unsafeAtomicAdd(&gram[b * 25 + i * 5 + jslot], D);
            }
        }
    }
}

// ---------------- Anderson solve + xk ----------------

__global__ void solve_kernel(const double* __restrict__ gram, float* __restrict__ alpha, int n) {
    int b = threadIdx.x;
    if (b >= BB) return;
    const int m = n + 1;
    double A[6][7];
    for (int i = 0; i < m; i++)
        for (int jj = 0; jj <= m; jj++) A[i][jj] = 0.0;
    for (int i = 1; i < m; i++) { A[0][i] = 1.0; A[i][0] = 1.0; }
    for (int i = 1; i < m; i++)
        for (int jj = 1; jj < m; jj++)
            A[i][jj] = gram[b * 25 + (i - 1) * 5 + (jj - 1)] + ((i == jj) ? LAMV : 0.0);
    A[0][m] = 1.0;
    for (int col = 0; col < m; col++) {
        int piv = col; double best = fabs(A[col][col]);
        for (int rr = col + 1; rr < m; rr++) {
            double tv = fabs(A[rr][col]);
            if (tv > best) { best = tv; piv = rr; }
        }
        if (piv != col)
            for (int cc = col; cc <= m; cc++) {
                double tmp = A[col][cc]; A[col][cc] = A[piv][cc]; A[piv][cc] = tmp;
            }
        double invp = 1.0 / A[col][col];
        for (int cc = col; cc <= m; cc++) A[col][cc] *= invp;
        for (int rr = 0; rr < m; rr++) {
            if (rr == col) continue;
            double f = A[rr][col];
            if (f != 0.0)
                for (int cc = col; cc <= m; cc++) A[rr][cc] = fma(-f, A[col][cc], A[rr][cc]);
        }
    }
    for (int i = 0; i < n; i++) alpha[b * 5 + i] = (float)A[i + 1][m];
}

// xk = sum alpha_j F_j, looped 8x8 elems/thread; block 0 zeroes gram row/col jz
__global__ __launch_bounds__(256) void xk_kernel(
    const bf16_t* __restrict__ Fb, const float* __restrict__ alpha,
    bf16_t* __restrict__ zcur, int n, double* __restrict__ gram, int jz, int nf)
{
    if (blockIdx.x == 0 && threadIdx.x < 8 * nf) {
        int b = threadIdx.x / nf, i = threadIdx.x % nf;
        gram[b * 25 + jz * 5 + i] = 0.0;
        gram[b * 25 + i * 5 + jz] = 0.0;
    }
    const int b = blockIdx.x / 75;
    float al[5];
    #pragma unroll
    for (int j = 0; j < 5; j++) al[j] = (j < n) ? alpha[b * 5 + j] : 0.f;
    const size_t base = (size_t)blockIdx.x * 16384 + (size_t)threadIdx.x * 8;
    for (int it = 0; it < 8; it++) {
        size_t idx = base + (size_t)it * 2048;
        float s[8] = {0.f, 0.f, 0.f, 0.f, 0.f, 0.f, 0.f, 0.f};
        #pragma unroll
        for (int j = 0; j < 5; j++) {
            if (j < n) {
                float f[8];
                ld8(Fb + (size_t)j * SLOT + idx, f);
                #pragma unroll
                for (int e = 0; e < 8; e++) s[e] = fmaf(f[e], al[j], s[e]);
            }
        }
        st8(zcur + idx, s);
    }
}

// ---------------- final linear (NHWC bf16 in) ----------------
__global__ __launch_bounds__(512) void fc_kernel(
    const bf16_t* __restrict__ zf, const float* __restrict__ fw,
    const float* __restrict__ fb, float* __restrict__ out)
{
    __shared__ bf16_t row[9600];
    __shared__ float fwT[2000];
    int tid = threadIdx.x;
    int b = blockIdx.x >> 7, hh = blockIdx.x & 127;
    size_t base = (((size_t)b * HH + hh) * WW) * 48;
    for (int i = tid; i < 2400; i += 512)
        *(ushort4*)&row[i * 4] = *(const ushort4*)(zf + base + (size_t)i * 4);
    for (int i = tid; i < 2000; i += 512) fwT[i] = fw[i];
    __syncthreads();
    if (tid < 480) {
        int c = tid % 48, o = tid / 48;
        float acc = fb[o];
        #pragma unroll 4
        for (int w = 0; w < 200; w++)
            acc = fmaf(b2f(row[w * 48 + c]), fwT[o * 200 + w], acc);
        out[(((size_t)b * 48 + c) * HH + hh) * 10 + o] = acc;
    }
}

// ---------------- host ----------------

static inline int imin(int a, int b) { return a < b ? a : b; }

extern "C" void kernel_launch(void* const* d_in, const int* in_sizes, int n_in,
                              void* d_out, int out_size, void* d_ws, size_t ws_size,
                              hipStream_t stream)
{
    const float* x   = (const float*)d_in[0];
    const float* w0  = (const float*)d_in[1];
    const float* b0  = (const float*)d_in[2];
    const float* bng = (const float*)d_in[3];
    const float* bnb = (const float*)d_in[4];
    const float* w1  = (const float*)d_in[5];
    const float* w2  = (const float*)d_in[6];
    const float* g1  = (const float*)d_in[7];
    const float* be1 = (const float*)d_in[8];
    const float* g2  = (const float*)d_in[9];
    const float* be2 = (const float*)d_in[10];
    const float* g3  = (const float*)d_in[11];
    const float* be3 = (const float*)d_in[12];
    const float* fcw = (const float*)d_in[13];
    const float* fcb = (const float*)d_in[14];
    float* out = (float*)d_out;

    bf16_t* h    = (bf16_t*)d_ws;           // SLOT    (NHWC)
    bf16_t* zcur = h + (size_t)SLOT;        // SLOT
    bf16_t* y64  = zcur + (size_t)SLOT;     // Y64SZ
    bf16_t* Fb   = y64 + (size_t)Y64SZ;     // 5*SLOT
    bf16_t* Gb   = Fb + 5 * (size_t)SLOT;   // 5*SLOT
    double* dstats = (double*)((char*)d_ws + BIGELEMS * 2);  // 9696 dbl: BN 96 + 25*384
    double* gram   = dstats + 9696;                          // 200 dbl
    float*  alpha  = (float*)(gram + 200);                   // 40 f
    bf16_t* apk1   = (bf16_t*)(alpha + 40);                  // 27648
    bf16_t* apk2   = apk1 + 27648;                           // 36864
    float*  scratch = (float*)Gb;  // conv0 raw fp32 (G region dead at that point)

    const size_t need = BIGELEMS * 2 + 9696 * 8 + 200 * 8 + 40 * 4 + (27648 + 36864) * 2;
    if (ws_size < need) return;

    const dim3 blk(256);
    const int CHUNKS16 = SLOT * 2 / 16 / 256;  // 4800

    zero_kernel<<<(19792 + 255) / 256, blk, 0, stream>>>((float*)dstats, 19792);
    pack_kernel<<<108, blk, 0, stream>>>(w1, apk1, 48, 64, 27648);
    pack_kernel<<<144, blk, 0, stream>>>(w2, apk2, 64, 48, 36864);
    fill16_kernel<<<CHUNKS16, blk, 0, stream>>>((float4*)zcur);

    // h = BN(conv0(x)+b0) in NHWC bf16
    conv0_kernel<<<BB * HH, blk, 0, stream>>>(x, w0, b0, scratch);
    bn_stats_kernel<<<dim3(100, BB), dim3(192), 0, stream>>>(scratch, dstats);
    bn_apply_kernel<<<SLOT / 1024, blk, 0, stream>>>(scratch, h, bng, bnb, dstats);

    int call = 0;
    auto resnet = [&](const bf16_t* zin, bf16_t* Fdst, bf16_t* Gdst, int jslot, int nf) {
        double* ds = dstats + 96 + 384 * call;  // ds1 = +0, ds2 = +128, ds3 = +256
        call++;
        dim3 cg(7, 16, BB);
        conv_mfma_kernel<48, 56, 64, 66, 8, true, false, false><<<cg, dim3(512), 0, stream>>>(
            zin, (const s8v*)apk1, nullptr, y64, ds, nullptr, nullptr, nullptr);
        conv_mfma_kernel<64, 72, 48, 50, 6, false, true, true><<<cg, dim3(512), 0, stream>>>(
            y64, (const s8v*)apk2, h, Fdst, ds + 128, ds, g1, be1);
        add_relu_gn2_kernel<<<dim3(100, BB), dim3(192), 0, stream>>>(
            Fdst, zin, ds + 128, g2, be2, ds + 256);
        gn3_gram_kernel<<<dim3(100, BB), dim3(192), 0, stream>>>(
            Fdst, zin, Fdst, Gdst, ds + 256, g3, be3, Gb, jslot, nf, gram);
    };

    // slot 0: X=0, F0=f(0), G0=F0 (gram[0,0] accumulated in gn3)
    resnet(zcur, Fb, Gb, 0, 1);
    // slot 1: X=F0, F1=f(F0), G1=F1-F0
    copy16_kernel<<<CHUNKS16, blk, 0, stream>>>((float4*)zcur, (const float4*)Fb);
    resnet(zcur, Fb + (size_t)SLOT, Gb + (size_t)SLOT, 1, 2);

    for (int k = 2; k <= 24; k++) {
        int n = imin(k, 5);
        int j = k % 5;
        int nf = imin(k + 1, 5);
        solve_kernel<<<1, 64, 0, stream>>>(gram, alpha, n);
        xk_kernel<<<600, blk, 0, stream>>>(Fb, alpha, zcur, n, gram, j, nf);
        if (k < 24)   // reference computes Fv at k=24 but never uses it
            resnet(zcur, Fb + (size_t)j * SLOT, Gb + (size_t)j * SLOT, j, nf);
    }

    // z_star = zcur; one extra f application into F slot 0 (no G, no gram)
    resnet(zcur, Fb, nullptr, 0, 0);

    // final linear: NHWC [8,128,200,48] x fw[10,200] -> out [8,48,128,10]
    fc_kernel<<<BB * HH, dim3(512), 0, stream>>>(Fb, fcw, fcb, out);
}